// Round 11
// baseline (708.854 us; speedup 1.0000x reference)
//
#include <hip/hip_runtime.h>
#include <hip/hip_bf16.h>
#include <hip/hip_fp16.h>
#include <math.h>

#define N_NODES 20000
#define N_EDGES 640000
#define ET_EDGES (N_EDGES + N_NODES)   // with self-loops
#define G_GRAPHS 64
#define NEG_SLOPE 0.2f

typedef __attribute__((ext_vector_type(8))) short s8v;   // 8 bf16 (4 VGPR)
typedef __attribute__((ext_vector_type(4))) float f4v;   // 4 fp32 acc

// fp32 -> bf16 (RNE) and back
__device__ __forceinline__ unsigned short bf_hi(float f) {
    union { float f; unsigned int u; } c; c.f = f;
    unsigned int r = (c.u + 0x7fffu + ((c.u >> 16) & 1u)) >> 16;
    return (unsigned short)r;
}
__device__ __forceinline__ float bf_f(unsigned short h) {
    union { unsigned int u; float f; } c; c.u = ((unsigned int)h) << 16;
    return c.f;
}

// ---------------- CSR construction (+ graph bounds folded in) ----------------

__global__ void hist_dst(const int* __restrict__ ei, int* __restrict__ cnt,
                         const int* __restrict__ batch, int* __restrict__ gstart) {
    int j = blockIdx.x * blockDim.x + threadIdx.x;
    if (blockIdx.x == 0 && threadIdx.x <= G_GRAPHS) {
        int g = threadIdx.x;
        int lo = 0, hi = N_NODES;
        while (lo < hi) {              // first i with batch[i] >= g
            int mid = (lo + hi) >> 1;
            if (batch[mid] < g) lo = mid + 1; else hi = mid;
        }
        gstart[g] = lo;
    }
    if (j >= ET_EDGES) return;
    int d = (j < N_EDGES) ? ei[N_EDGES + j] : (j - N_EDGES);
    atomicAdd(&cnt[d], 1);
}

__global__ __launch_bounds__(1024) void scan_rowptr(const int* __restrict__ cnt,
                                                    int* __restrict__ row_ptr) {
    __shared__ int sums[1024];
    const int n = N_NODES;
    const int CH = (n + 1023) / 1024;   // 20
    int t = threadIdx.x;
    int base = t * CH;
    int s = 0;
    for (int i = 0; i < CH; ++i) {
        int idx = base + i;
        if (idx < n) s += cnt[idx];
    }
    sums[t] = s;
    __syncthreads();
    for (int o = 1; o < 1024; o <<= 1) {
        int v = (t >= o) ? sums[t - o] : 0;
        __syncthreads();
        sums[t] += v;
        __syncthreads();
    }
    int run = (t == 0) ? 0 : sums[t - 1];
    for (int i = 0; i < CH; ++i) {
        int idx = base + i;
        if (idx < n) { row_ptr[idx] = run; run += cnt[idx]; }
    }
    if (t == 1023) row_ptr[n] = sums[1023];
}

__global__ void fill_csr(const int* __restrict__ ei, const int* __restrict__ row_ptr,
                         int* __restrict__ cur, int* __restrict__ col) {
    int j = blockIdx.x * blockDim.x + threadIdx.x;
    if (j >= ET_EDGES) return;
    int s, d;
    if (j < N_EDGES) { s = ei[j]; d = ei[N_EDGES + j]; }
    else             { s = d = j - N_EDGES; }
    int pos = row_ptr[d] + atomicAdd(&cur[d], 1);
    col[pos] = s;
}

// ---------------- fused prep: x/W splits + buffer zeroing -------------------

__global__ void prep_split(const float* __restrict__ x,
                           const float* __restrict__ W1, const float* __restrict__ W2,
                           const float* __restrict__ W3,
                           unsigned short* __restrict__ xh, unsigned short* __restrict__ xl,
                           unsigned short* __restrict__ w1h, unsigned short* __restrict__ w1l,
                           unsigned short* __restrict__ w2h, unsigned short* __restrict__ w2l,
                           unsigned short* __restrict__ w3h, unsigned short* __restrict__ w3l,
                           int* __restrict__ cntcur, float* __restrict__ gout,
                           float* __restrict__ alphaz) {
    int idx = blockIdx.x * blockDim.x + threadIdx.x;
    if (idx < 640000) {                     // x: [20000*128] f32 -> hi/lo, vec4
        int i = idx * 4;
        float4 v = *(const float4*)&x[i];
        ushort4 h, l;
        h.x = bf_hi(v.x); l.x = bf_hi(v.x - bf_f(h.x));
        h.y = bf_hi(v.y); l.y = bf_hi(v.y - bf_f(h.y));
        h.z = bf_hi(v.z); l.z = bf_hi(v.z - bf_f(h.z));
        h.w = bf_hi(v.w); l.w = bf_hi(v.w - bf_f(h.w));
        *(ushort4*)&xh[i] = h;
        *(ushort4*)&xl[i] = l;
        return;
    }
    idx -= 640000;
    if (idx < 32768) {                      // W1 [128][256] -> [256][128]
        int k = idx / 256, n = idx % 256;
        float v = W1[idx];
        unsigned short h = bf_hi(v);
        w1h[n * 128 + k] = h;
        w1l[n * 128 + k] = bf_hi(v - bf_f(h));
        return;
    }
    idx -= 32768;
    if (idx < 65536) {                      // W2 [256][256] -> [256][256]
        int k = idx / 256, n = idx % 256;
        float v = W2[idx];
        unsigned short h = bf_hi(v);
        w2h[n * 256 + k] = h;
        w2l[n * 256 + k] = bf_hi(v - bf_f(h));
        return;
    }
    idx -= 65536;
    if (idx < 32768) {                      // W3 [256][128] -> [128][256]
        int k = idx / 128, n = idx % 128;
        float v = W3[idx];
        unsigned short h = bf_hi(v);
        w3h[n * 256 + k] = h;
        w3l[n * 256 + k] = bf_hi(v - bf_f(h));
        return;
    }
    idx -= 32768;
    if (idx < 10000) {                      // zero cnt+cur (40000 ints, vec4)
        *(int4*)&cntcur[idx * 4] = make_int4(0, 0, 0, 0);
        return;
    }
    idx -= 10000;
    if (idx < 2048) {                       // zero gout (8192 floats, vec4)
        *(float4*)&gout[idx * 4] = make_float4(0.f, 0.f, 0.f, 0.f);
        return;
    }
    idx -= 2048;
    if (idx < 90000) {                      // zero alpha buffers (360000 f32)
        *(float4*)&alphaz[idx * 4] = make_float4(0.f, 0.f, 0.f, 0.f);
    }
}

// ---------------- split-bf16 MFMA GEMM + fused alpha epilogue ---------------
// C = Ah*Bh + Ah*Bl + Al*Bh (lo*lo ~2^-18 rel, dropped). fp32 accumulate.
// C is written as FP16 (R11): it is consumed only as the aggregate's gather
// table; fp16 halves gather bytes+instructions there. Alpha epilogue uses the
// f32 accumulators (unaffected). Both waves of the 64-col tile atomicAdd
// their 32-col partial alpha dots into pre-zeroed asT/adT (R10 fix).

#define LDT 40

template <int CPH>
__global__ __launch_bounds__(256) void gemm_split(
        const unsigned short* __restrict__ Ah, const unsigned short* __restrict__ Al,
        const unsigned short* __restrict__ Bh, const unsigned short* __restrict__ Bl,
        __half* __restrict__ C, int M, int Nc, int K,
        const float* __restrict__ a_src, const float* __restrict__ a_dst,
        float* __restrict__ asT, float* __restrict__ adT) {
    __shared__ unsigned short lAh[128 * LDT];
    __shared__ unsigned short lAl[128 * LDT];
    __shared__ unsigned short lBh[64 * LDT];
    __shared__ unsigned short lBl[64 * LDT];
    int bm = blockIdx.x * 128, bn = blockIdx.y * 64;
    int t = threadIdx.x, w = t >> 6, lane = t & 63;
    int wm = (w >> 1) * 64, wn = (w & 1) * 32;

    f4v acc[4][2] = {};

    int sr = t >> 1, sk = (t & 1) << 4;     // A: row, k-offset {0,16}
    int br = t >> 2, bk = (t & 3) << 3;     // B: row, k-offset {0,8,16,24}
    int ar = bm + sr; if (ar >= M) ar = M - 1;
    const unsigned short* pAh = Ah + (size_t)ar * K + sk;
    const unsigned short* pAl = Al + (size_t)ar * K + sk;
    const unsigned short* pBh = Bh + (size_t)(bn + br) * K + bk;
    const unsigned short* pBl = Bl + (size_t)(bn + br) * K + bk;

    int fr = lane & 15, fk = (lane >> 4) << 3;

    for (int k0 = 0; k0 < K; k0 += 32) {
        uint4 vh0 = *(const uint4*)(pAh + k0);
        uint4 vh1 = *(const uint4*)(pAh + k0 + 8);
        uint4 vl0 = *(const uint4*)(pAl + k0);
        uint4 vl1 = *(const uint4*)(pAl + k0 + 8);
        uint4 wh  = *(const uint4*)(pBh + k0);
        uint4 wl  = *(const uint4*)(pBl + k0);
        __syncthreads();
        *(uint4*)&lAh[sr * LDT + sk]     = vh0;
        *(uint4*)&lAh[sr * LDT + sk + 8] = vh1;
        *(uint4*)&lAl[sr * LDT + sk]     = vl0;
        *(uint4*)&lAl[sr * LDT + sk + 8] = vl1;
        *(uint4*)&lBh[br * LDT + bk] = wh;
        *(uint4*)&lBl[br * LDT + bk] = wl;
        __syncthreads();

        s8v a_h[4], a_l[4], b_h[2], b_l[2];
        #pragma unroll
        for (int mi = 0; mi < 4; ++mi) {
            a_h[mi] = *(const s8v*)&lAh[(wm + mi * 16 + fr) * LDT + fk];
            a_l[mi] = *(const s8v*)&lAl[(wm + mi * 16 + fr) * LDT + fk];
        }
        #pragma unroll
        for (int nj = 0; nj < 2; ++nj) {
            b_h[nj] = *(const s8v*)&lBh[(wn + nj * 16 + fr) * LDT + fk];
            b_l[nj] = *(const s8v*)&lBl[(wn + nj * 16 + fr) * LDT + fk];
        }
        #pragma unroll
        for (int mi = 0; mi < 4; ++mi)
            #pragma unroll
            for (int nj = 0; nj < 2; ++nj) {
                acc[mi][nj] = __builtin_amdgcn_mfma_f32_16x16x32_bf16(
                    a_h[mi], b_h[nj], acc[mi][nj], 0, 0, 0);
                acc[mi][nj] = __builtin_amdgcn_mfma_f32_16x16x32_bf16(
                    a_h[mi], b_l[nj], acc[mi][nj], 0, 0, 0);
                acc[mi][nj] = __builtin_amdgcn_mfma_f32_16x16x32_bf16(
                    a_l[mi], b_h[nj], acc[mi][nj], 0, 0, 0);
            }
    }

    // C/D layout: col = lane&15, row = (lane>>4)*4 + q  [verified gfx950]
    #pragma unroll
    for (int mi = 0; mi < 4; ++mi)
        #pragma unroll
        for (int nj = 0; nj < 2; ++nj) {
            int row0 = bm + wm + mi * 16 + (lane >> 4) * 4;
            int colc = bn + wn + nj * 16 + (lane & 15);
            #pragma unroll
            for (int q = 0; q < 4; ++q) {
                int r = row0 + q;
                if (r < M) C[(size_t)r * Nc + colc] = __float2half(acc[mi][nj][q]);
            }
        }

    // ---- fused alpha epilogue: per-wave 32-col partial dot, atomic combine --
    float av_s[2], av_d[2];
    #pragma unroll
    for (int nj = 0; nj < 2; ++nj) {
        int aidx = bn + wn + nj * 16 + fr;
        av_s[nj] = a_src[aidx];
        av_d[nj] = a_dst[aidx];
    }
    int head = bn / CPH;
    #pragma unroll
    for (int mi = 0; mi < 4; ++mi) {
        #pragma unroll
        for (int q = 0; q < 4; ++q) {
            float ps = acc[mi][0][q] * av_s[0] + acc[mi][1][q] * av_s[1];
            float pd = acc[mi][0][q] * av_d[0] + acc[mi][1][q] * av_d[1];
            #pragma unroll
            for (int o = 1; o < 16; o <<= 1) {
                ps += __shfl_xor(ps, o);
                pd += __shfl_xor(pd, o);
            }
            if (fr == 0) {
                int r = bm + wm + mi * 16 + (lane >> 4) * 4 + q;
                if (r < M) {
                    atomicAdd(&asT[(size_t)head * M + r], ps);
                    atomicAdd(&adT[(size_t)head * M + r], pd);
                }
            }
        }
    }
}

// ---------------- channel-sliced softmax-aggregate, fp16 gather table -------
// R3 structure (NSLICE=4, fused softmax, LDS-staged metadata — the measured
// optimum across R4-R8 probes) with the h table in FP16 (R11): 16B lane-load
// covers 8 channels -> gather instructions halve (CL=8, E=8 -> ~5 groups per
// window vs 9), gather bytes halve, per-slice working set 2.5MB fits the
// 4MB XCD L2. FMAs take the fp16 operand via v_fma_mix (half2->float).
// POOL=true (layer 3): epilogue also atomicAdds o/cnt(g) into gout —
// replaces the pool_mean4 dispatch.

template <int SCH, int F, int HEADS, bool DO_ELU, bool SPLIT, bool POOL>
__global__ __launch_bounds__(256) void gat_aggregate6(
        const __half* __restrict__ h,     // [N, F] fp16
        const float* __restrict__ asT,    // [HEADS][N]
        const float* __restrict__ adT,    // [HEADS][N]
        const int* __restrict__ row_ptr,
        const int* __restrict__ col,
        const float* __restrict__ bias,   // [F]
        float* __restrict__ out,          // [N, F]   (SPLIT=false)
        unsigned short* __restrict__ oh,  // [N, F]   (SPLIT=true)
        unsigned short* __restrict__ ol,
        const int* __restrict__ batch,    // POOL only
        const int* __restrict__ gstart,   // POOL only
        float* __restrict__ gout) {       // POOL only
    constexpr int CL = SCH / 8;           // lanes per edge (8 or 4): 16B = 8 fp16
    constexpr int E  = 64 / CL;           // parallel edges (8 or 16)
    constexpr int CPH = F / HEADS;        // channels per head
    __shared__ int   s_off[4][64];
    __shared__ float s_p[4][64];
    int slice = blockIdx.x & 3;           // NSLICE == 4
    int ng = blockIdx.x >> 2;
    int wid = threadIdx.x >> 6, lane = threadIdx.x & 63;
    int v = ng * 4 + wid;
    if (v >= N_NODES) return;
    int head = (slice * SCH) / CPH;       // layers 1/2: slice; layer 3: 0
    int eg = lane / CL, cl = lane % CL;
    int r0 = row_ptr[v], r1 = row_ptr[v + 1];
    float ad = adT[head * N_NODES + v];
    const float* asrc = asT + head * N_NODES;
    float acc[8] = {};
    float lsum = 0.f;
    const char* hb = (const char*)h + (slice * SCH + cl * 8) * 2;

#define HFMA(pk, hw)                                                       \
    { const __half2* q2 = (const __half2*)&(hw);                           \
      float2 f0 = __half22float2(q2[0]);                                   \
      float2 f1 = __half22float2(q2[1]);                                   \
      float2 f2 = __half22float2(q2[2]);                                   \
      float2 f3 = __half22float2(q2[3]);                                   \
      acc[0] = fmaf(pk, f0.x, acc[0]); acc[1] = fmaf(pk, f0.y, acc[1]);    \
      acc[2] = fmaf(pk, f1.x, acc[2]); acc[3] = fmaf(pk, f1.y, acc[3]);    \
      acc[4] = fmaf(pk, f2.x, acc[4]); acc[5] = fmaf(pk, f2.y, acc[5]);    \
      acc[6] = fmaf(pk, f3.x, acc[6]); acc[7] = fmaf(pk, f3.y, acc[7]); }

#define GATHER4(gg)                                                        \
    {                                                                      \
        int k0 = ((gg) + 0) * E + eg;                                      \
        int k1 = ((gg) + 1) * E + eg;                                      \
        int k2 = ((gg) + 2) * E + eg;                                      \
        int k3 = ((gg) + 3) * E + eg;                                      \
        float p0 = s_p[wid][k0]; int o0 = s_off[wid][k0];                  \
        float p1 = s_p[wid][k1]; int o1 = s_off[wid][k1];                  \
        float p2 = s_p[wid][k2]; int o2 = s_off[wid][k2];                  \
        float p3 = s_p[wid][k3]; int o3 = s_off[wid][k3];                  \
        uint4 h0 = *(const uint4*)(hb + o0);                               \
        uint4 h1 = *(const uint4*)(hb + o1);                               \
        uint4 h2 = *(const uint4*)(hb + o2);                               \
        uint4 h3 = *(const uint4*)(hb + o3);                               \
        HFMA(p0, h0); HFMA(p1, h1); HFMA(p2, h2); HFMA(p3, h3);            \
    }

    for (int base = r0; base < r1; base += 64) {
        int j = base + lane;
        bool valid = j < r1;
        int s = col[valid ? j : r0];
        float e = asrc[s] + ad;
        e = (e > 0.f) ? e : NEG_SLOPE * e;
        float p = valid ? __expf(e) : 0.f;
        lsum += p;
        s_p[wid][lane] = p;
        s_off[wid][lane] = s * (F * 2);   // byte offset of fp16 row s
        // wave-synchronous: wid-private LDS rows, no barrier needed

        int nk = min(64, r1 - base);
        int nkg = (nk + E - 1) / E;       // <= 64/E groups (8 or 4)
        int g = 0;
        for (; g + 4 <= nkg; g += 4) GATHER4(g);
        if (g < nkg) GATHER4(g);          // ragged tail: pad groups have p==0
    }
#undef GATHER4
#undef HFMA

    // full-wave softmax denominator
    #pragma unroll
    for (int o = 32; o; o >>= 1) lsum += __shfl_xor(lsum, o);
    // reduce acc across edge groups (lanes differing in bits >= log2(CL))
    #pragma unroll
    for (int c = 0; c < 8; ++c) {
        #pragma unroll
        for (int o = CL; o < 64; o <<= 1) acc[c] += __shfl_xor(acc[c], o);
    }
    if (eg == 0) {
        float inv = 1.f / (lsum + 1e-16f);
        int ch0 = slice * SCH + cl * 8;
        float o8[8];
        #pragma unroll
        for (int c = 0; c < 8; ++c) {
            float o = acc[c] * inv + bias[ch0 + c];
            if (DO_ELU) o = (o > 0.f) ? o : expm1f(o);
            o8[c] = o;
        }
        if constexpr (SPLIT) {
            unsigned short hv[8], lv[8];
            #pragma unroll
            for (int c = 0; c < 8; ++c) {
                hv[c] = bf_hi(o8[c]);
                lv[c] = bf_hi(o8[c] - bf_f(hv[c]));
            }
            *(uint4*)&oh[(size_t)v * F + ch0] = *(const uint4*)hv;
            *(uint4*)&ol[(size_t)v * F + ch0] = *(const uint4*)lv;
        } else {
            *(float4*)&out[(size_t)v * F + ch0]     = *(const float4*)&o8[0];
            *(float4*)&out[(size_t)v * F + ch0 + 4] = *(const float4*)&o8[4];
        }
        if constexpr (POOL) {
            int g = batch[v];
            float invc = 1.f / fmaxf((float)(gstart[g + 1] - gstart[g]), 1.0f);
            #pragma unroll
            for (int c = 0; c < 8; ++c)
                atomicAdd(&gout[g * 128 + ch0 + c], o8[c] * invc);
        }
    }
}

// ---------------- launch ----------------

static inline size_t align_up(size_t x, size_t a) { return (x + a - 1) & ~(a - 1); }

extern "C" void kernel_launch(void* const* d_in, const int* in_sizes, int n_in,
                              void* d_out, int out_size, void* d_ws, size_t ws_size,
                              hipStream_t stream) {
    const float* x   = (const float*)d_in[0];
    const int*   ei  = (const int*)d_in[1];
    const int*   bat = (const int*)d_in[2];
    const float* W1  = (const float*)d_in[3];
    const float* as1 = (const float*)d_in[4];
    const float* ad1 = (const float*)d_in[5];
    const float* b1  = (const float*)d_in[6];
    const float* W2  = (const float*)d_in[7];
    const float* as2 = (const float*)d_in[8];
    const float* ad2 = (const float*)d_in[9];
    const float* b2  = (const float*)d_in[10];
    const float* W3  = (const float*)d_in[11];
    const float* as3 = (const float*)d_in[12];
    const float* ad3 = (const float*)d_in[13];
    const float* b3  = (const float*)d_in[14];

    float* gout = (float*)d_out;                     // [G,128]
    float* hout = (float*)d_out + G_GRAPHS * 128;    // [N,128]

    char* w = (char*)d_ws;
    size_t o = 0;
    __half* bufA = (__half*)(w + o);         o = align_up(o + (size_t)N_NODES * 256 * 2, 256);
    unsigned short* Bh = (unsigned short*)(w + o); o = align_up(o + (size_t)N_NODES * 256 * 2, 256);
    unsigned short* Bl = (unsigned short*)(w + o); o = align_up(o + (size_t)N_NODES * 256 * 2, 256);
    unsigned short* xh = (unsigned short*)(w + o); o = align_up(o + (size_t)N_NODES * 128 * 2, 256);
    unsigned short* xl = (unsigned short*)(w + o); o = align_up(o + (size_t)N_NODES * 128 * 2, 256);
    unsigned short* Wt1h = (unsigned short*)(w + o); o = align_up(o + (size_t)256 * 128 * 2, 256);
    unsigned short* Wt1l = (unsigned short*)(w + o); o = align_up(o + (size_t)256 * 128 * 2, 256);
    unsigned short* Wt2h = (unsigned short*)(w + o); o = align_up(o + (size_t)256 * 256 * 2, 256);
    unsigned short* Wt2l = (unsigned short*)(w + o); o = align_up(o + (size_t)256 * 256 * 2, 256);
    unsigned short* Wt3h = (unsigned short*)(w + o); o = align_up(o + (size_t)128 * 256 * 2, 256);
    unsigned short* Wt3l = (unsigned short*)(w + o); o = align_up(o + (size_t)128 * 256 * 2, 256);
    // per-layer alpha buffers, CONTIGUOUS (zeroed as one 360000-f32 block)
    float* alpha = (float*)(w + o);
    float* asv1 = alpha;                  // [4][N]
    float* adv1 = alpha + 4 * N_NODES;    // [4][N]
    float* asv2 = alpha + 8 * N_NODES;    // [4][N]
    float* adv2 = alpha + 12 * N_NODES;   // [4][N]
    float* asv3 = alpha + 16 * N_NODES;   // [N]
    float* adv3 = alpha + 17 * N_NODES;   // [N]
    o = align_up(o + (size_t)18 * N_NODES * 4, 256);
    int* row_ptr = (int*)(w + o);  o = align_up(o + (size_t)(N_NODES + 1) * 4, 256);
    int* col     = (int*)(w + o);  o = align_up(o + (size_t)ET_EDGES * 4, 256);
    int* cnt     = (int*)(w + o);  o += (size_t)N_NODES * 4;        // cnt+cur contiguous
    int* cur     = (int*)(w + o);  o = align_up(o + (size_t)N_NODES * 4, 256);
    int* gstart  = (int*)(w + o);  o = align_up(o + (size_t)(G_GRAPHS + 1) * 4, 256);

    // ---- fused prep (splits + zeroing) + CSR build ----
    {
        int total = 640000 + 32768 + 65536 + 32768 + 10000 + 2048 + 90000;
        prep_split<<<(total + 255) / 256, 256, 0, stream>>>(
            x, W1, W2, W3, xh, xl, Wt1h, Wt1l, Wt2h, Wt2l, Wt3h, Wt3l, cnt, gout, alpha);
    }
    hist_dst<<<(ET_EDGES + 255) / 256, 256, 0, stream>>>(ei, cnt, bat, gstart);
    scan_rowptr<<<1, 1024, 0, stream>>>(cnt, row_ptr);
    fill_csr<<<(ET_EDGES + 255) / 256, 256, 0, stream>>>(ei, row_ptr, cur, col);

    int gm = (N_NODES + 127) / 128;   // 157
    int nb = (N_NODES + 3) / 4;       // 4 nodes per block
    int nbs = nb * 4;                 // x4 channel slices

    // ---- layer 1: 128 -> 4x64 (alpha fused into GEMM epilogue) ----
    gemm_split<64><<<dim3(gm, 4), 256, 0, stream>>>(
        xh, xl, Wt1h, Wt1l, bufA, N_NODES, 256, 128, as1, ad1, asv1, adv1);
    gat_aggregate6<64, 256, 4, true, true, false><<<nbs, 256, 0, stream>>>(
        bufA, asv1, adv1, row_ptr, col, b1, nullptr, Bh, Bl, nullptr, nullptr, nullptr);

    // ---- layer 2: 256 -> 4x64 ----
    gemm_split<64><<<dim3(gm, 4), 256, 0, stream>>>(
        Bh, Bl, Wt2h, Wt2l, bufA, N_NODES, 256, 256, as2, ad2, asv2, adv2);
    gat_aggregate6<64, 256, 4, true, true, false><<<nbs, 256, 0, stream>>>(
        bufA, asv2, adv2, row_ptr, col, b2, nullptr, Bh, Bl, nullptr, nullptr, nullptr);

    // ---- layer 3: 256 -> 128 (1 head; pool fused into epilogue) ----
    gemm_split<128><<<dim3(gm, 2), 256, 0, stream>>>(
        Bh, Bl, Wt3h, Wt3l, bufA, N_NODES, 128, 256, as3, ad3, asv3, adv3);
    gat_aggregate6<32, 128, 1, false, false, true><<<nbs, 256, 0, stream>>>(
        bufA, asv3, adv3, row_ptr, col, b3, hout, nullptr, nullptr, bat, gstart, gout);
}

// Round 12
// 443.891 us; speedup vs baseline: 1.5969x; 1.5969x over previous
//
#include <hip/hip_runtime.h>
#include <hip/hip_bf16.h>
#include <hip/hip_fp16.h>
#include <math.h>

#define N_NODES 20000
#define N_EDGES 640000
#define ET_EDGES (N_EDGES + N_NODES)   // with self-loops
#define G_GRAPHS 64
#define NEG_SLOPE 0.2f

typedef __attribute__((ext_vector_type(8))) short s8v;   // 8 bf16 (4 VGPR)
typedef __attribute__((ext_vector_type(4))) float f4v;   // 4 fp32 acc

// fp32 -> bf16 (RNE) and back
__device__ __forceinline__ unsigned short bf_hi(float f) {
    union { float f; unsigned int u; } c; c.f = f;
    unsigned int r = (c.u + 0x7fffu + ((c.u >> 16) & 1u)) >> 16;
    return (unsigned short)r;
}
__device__ __forceinline__ float bf_f(unsigned short h) {
    union { unsigned int u; float f; } c; c.u = ((unsigned int)h) << 16;
    return c.f;
}

// ---------------- CSR construction (+ graph bounds folded in) ----------------

__global__ void hist_dst(const int* __restrict__ ei, int* __restrict__ cnt,
                         const int* __restrict__ batch, int* __restrict__ gstart) {
    int j = blockIdx.x * blockDim.x + threadIdx.x;
    if (blockIdx.x == 0 && threadIdx.x <= G_GRAPHS) {
        int g = threadIdx.x;
        int lo = 0, hi = N_NODES;
        while (lo < hi) {              // first i with batch[i] >= g
            int mid = (lo + hi) >> 1;
            if (batch[mid] < g) lo = mid + 1; else hi = mid;
        }
        gstart[g] = lo;
    }
    if (j >= ET_EDGES) return;
    int d = (j < N_EDGES) ? ei[N_EDGES + j] : (j - N_EDGES);
    atomicAdd(&cnt[d], 1);
}

__global__ __launch_bounds__(1024) void scan_rowptr(const int* __restrict__ cnt,
                                                    int* __restrict__ row_ptr) {
    __shared__ int sums[1024];
    const int n = N_NODES;
    const int CH = (n + 1023) / 1024;   // 20
    int t = threadIdx.x;
    int base = t * CH;
    int s = 0;
    for (int i = 0; i < CH; ++i) {
        int idx = base + i;
        if (idx < n) s += cnt[idx];
    }
    sums[t] = s;
    __syncthreads();
    for (int o = 1; o < 1024; o <<= 1) {
        int v = (t >= o) ? sums[t - o] : 0;
        __syncthreads();
        sums[t] += v;
        __syncthreads();
    }
    int run = (t == 0) ? 0 : sums[t - 1];
    for (int i = 0; i < CH; ++i) {
        int idx = base + i;
        if (idx < n) { row_ptr[idx] = run; run += cnt[idx]; }
    }
    if (t == 1023) row_ptr[n] = sums[1023];
}

__global__ void fill_csr(const int* __restrict__ ei, const int* __restrict__ row_ptr,
                         int* __restrict__ cur, int* __restrict__ col) {
    int j = blockIdx.x * blockDim.x + threadIdx.x;
    if (j >= ET_EDGES) return;
    int s, d;
    if (j < N_EDGES) { s = ei[j]; d = ei[N_EDGES + j]; }
    else             { s = d = j - N_EDGES; }
    int pos = row_ptr[d] + atomicAdd(&cur[d], 1);
    col[pos] = s;
}

// ---------------- fused prep: x/W splits + buffer zeroing -------------------

__global__ void prep_split(const float* __restrict__ x,
                           const float* __restrict__ W1, const float* __restrict__ W2,
                           const float* __restrict__ W3,
                           unsigned short* __restrict__ xh, unsigned short* __restrict__ xl,
                           unsigned short* __restrict__ w1h, unsigned short* __restrict__ w1l,
                           unsigned short* __restrict__ w2h, unsigned short* __restrict__ w2l,
                           unsigned short* __restrict__ w3h, unsigned short* __restrict__ w3l,
                           int* __restrict__ cntcur, float* __restrict__ gout,
                           float* __restrict__ alphaz) {
    int idx = blockIdx.x * blockDim.x + threadIdx.x;
    if (idx < 640000) {                     // x: [20000*128] f32 -> hi/lo, vec4
        int i = idx * 4;
        float4 v = *(const float4*)&x[i];
        ushort4 h, l;
        h.x = bf_hi(v.x); l.x = bf_hi(v.x - bf_f(h.x));
        h.y = bf_hi(v.y); l.y = bf_hi(v.y - bf_f(h.y));
        h.z = bf_hi(v.z); l.z = bf_hi(v.z - bf_f(h.z));
        h.w = bf_hi(v.w); l.w = bf_hi(v.w - bf_f(h.w));
        *(ushort4*)&xh[i] = h;
        *(ushort4*)&xl[i] = l;
        return;
    }
    idx -= 640000;
    if (idx < 32768) {                      // W1 [128][256] -> [256][128]
        int k = idx / 256, n = idx % 256;
        float v = W1[idx];
        unsigned short h = bf_hi(v);
        w1h[n * 128 + k] = h;
        w1l[n * 128 + k] = bf_hi(v - bf_f(h));
        return;
    }
    idx -= 32768;
    if (idx < 65536) {                      // W2 [256][256] -> [256][256]
        int k = idx / 256, n = idx % 256;
        float v = W2[idx];
        unsigned short h = bf_hi(v);
        w2h[n * 256 + k] = h;
        w2l[n * 256 + k] = bf_hi(v - bf_f(h));
        return;
    }
    idx -= 65536;
    if (idx < 32768) {                      // W3 [256][128] -> [128][256]
        int k = idx / 128, n = idx % 128;
        float v = W3[idx];
        unsigned short h = bf_hi(v);
        w3h[n * 256 + k] = h;
        w3l[n * 256 + k] = bf_hi(v - bf_f(h));
        return;
    }
    idx -= 32768;
    if (idx < 10000) {                      // zero cnt+cur (40000 ints, vec4)
        *(int4*)&cntcur[idx * 4] = make_int4(0, 0, 0, 0);
        return;
    }
    idx -= 10000;
    if (idx < 2048) {                       // zero gout (8192 floats, vec4)
        *(float4*)&gout[idx * 4] = make_float4(0.f, 0.f, 0.f, 0.f);
        return;
    }
    idx -= 2048;
    if (idx < 90000) {                      // zero alpha buffers (360000 f32)
        *(float4*)&alphaz[idx * 4] = make_float4(0.f, 0.f, 0.f, 0.f);
    }
}

// ---------------- split-bf16 MFMA GEMM + fused alpha epilogue ---------------
// C = Ah*Bh + Ah*Bl + Al*Bh (lo*lo ~2^-18 rel, dropped). fp32 accumulate.
// C written as FP16 (gather table; R11-validated: absmax unchanged 1.22e-4).
// Both waves of the 64-col tile atomicAdd their 32-col partial alpha dots
// into pre-zeroed asT/adT (R10 fix).

#define LDT 40

template <int CPH>
__global__ __launch_bounds__(256) void gemm_split(
        const unsigned short* __restrict__ Ah, const unsigned short* __restrict__ Al,
        const unsigned short* __restrict__ Bh, const unsigned short* __restrict__ Bl,
        __half* __restrict__ C, int M, int Nc, int K,
        const float* __restrict__ a_src, const float* __restrict__ a_dst,
        float* __restrict__ asT, float* __restrict__ adT) {
    __shared__ unsigned short lAh[128 * LDT];
    __shared__ unsigned short lAl[128 * LDT];
    __shared__ unsigned short lBh[64 * LDT];
    __shared__ unsigned short lBl[64 * LDT];
    int bm = blockIdx.x * 128, bn = blockIdx.y * 64;
    int t = threadIdx.x, w = t >> 6, lane = t & 63;
    int wm = (w >> 1) * 64, wn = (w & 1) * 32;

    f4v acc[4][2] = {};

    int sr = t >> 1, sk = (t & 1) << 4;     // A: row, k-offset {0,16}
    int br = t >> 2, bk = (t & 3) << 3;     // B: row, k-offset {0,8,16,24}
    int ar = bm + sr; if (ar >= M) ar = M - 1;
    const unsigned short* pAh = Ah + (size_t)ar * K + sk;
    const unsigned short* pAl = Al + (size_t)ar * K + sk;
    const unsigned short* pBh = Bh + (size_t)(bn + br) * K + bk;
    const unsigned short* pBl = Bl + (size_t)(bn + br) * K + bk;

    int fr = lane & 15, fk = (lane >> 4) << 3;

    for (int k0 = 0; k0 < K; k0 += 32) {
        uint4 vh0 = *(const uint4*)(pAh + k0);
        uint4 vh1 = *(const uint4*)(pAh + k0 + 8);
        uint4 vl0 = *(const uint4*)(pAl + k0);
        uint4 vl1 = *(const uint4*)(pAl + k0 + 8);
        uint4 wh  = *(const uint4*)(pBh + k0);
        uint4 wl  = *(const uint4*)(pBl + k0);
        __syncthreads();
        *(uint4*)&lAh[sr * LDT + sk]     = vh0;
        *(uint4*)&lAh[sr * LDT + sk + 8] = vh1;
        *(uint4*)&lAl[sr * LDT + sk]     = vl0;
        *(uint4*)&lAl[sr * LDT + sk + 8] = vl1;
        *(uint4*)&lBh[br * LDT + bk] = wh;
        *(uint4*)&lBl[br * LDT + bk] = wl;
        __syncthreads();

        s8v a_h[4], a_l[4], b_h[2], b_l[2];
        #pragma unroll
        for (int mi = 0; mi < 4; ++mi) {
            a_h[mi] = *(const s8v*)&lAh[(wm + mi * 16 + fr) * LDT + fk];
            a_l[mi] = *(const s8v*)&lAl[(wm + mi * 16 + fr) * LDT + fk];
        }
        #pragma unroll
        for (int nj = 0; nj < 2; ++nj) {
            b_h[nj] = *(const s8v*)&lBh[(wn + nj * 16 + fr) * LDT + fk];
            b_l[nj] = *(const s8v*)&lBl[(wn + nj * 16 + fr) * LDT + fk];
        }
        #pragma unroll
        for (int mi = 0; mi < 4; ++mi)
            #pragma unroll
            for (int nj = 0; nj < 2; ++nj) {
                acc[mi][nj] = __builtin_amdgcn_mfma_f32_16x16x32_bf16(
                    a_h[mi], b_h[nj], acc[mi][nj], 0, 0, 0);
                acc[mi][nj] = __builtin_amdgcn_mfma_f32_16x16x32_bf16(
                    a_h[mi], b_l[nj], acc[mi][nj], 0, 0, 0);
                acc[mi][nj] = __builtin_amdgcn_mfma_f32_16x16x32_bf16(
                    a_l[mi], b_h[nj], acc[mi][nj], 0, 0, 0);
            }
    }

    // C/D layout: col = lane&15, row = (lane>>4)*4 + q  [verified gfx950]
    #pragma unroll
    for (int mi = 0; mi < 4; ++mi)
        #pragma unroll
        for (int nj = 0; nj < 2; ++nj) {
            int row0 = bm + wm + mi * 16 + (lane >> 4) * 4;
            int colc = bn + wn + nj * 16 + (lane & 15);
            #pragma unroll
            for (int q = 0; q < 4; ++q) {
                int r = row0 + q;
                if (r < M) C[(size_t)r * Nc + colc] = __float2half(acc[mi][nj][q]);
            }
        }

    // ---- fused alpha epilogue: per-wave 32-col partial dot, atomic combine --
    float av_s[2], av_d[2];
    #pragma unroll
    for (int nj = 0; nj < 2; ++nj) {
        int aidx = bn + wn + nj * 16 + fr;
        av_s[nj] = a_src[aidx];
        av_d[nj] = a_dst[aidx];
    }
    int head = bn / CPH;
    #pragma unroll
    for (int mi = 0; mi < 4; ++mi) {
        #pragma unroll
        for (int q = 0; q < 4; ++q) {
            float ps = acc[mi][0][q] * av_s[0] + acc[mi][1][q] * av_s[1];
            float pd = acc[mi][0][q] * av_d[0] + acc[mi][1][q] * av_d[1];
            #pragma unroll
            for (int o = 1; o < 16; o <<= 1) {
                ps += __shfl_xor(ps, o);
                pd += __shfl_xor(pd, o);
            }
            if (fr == 0) {
                int r = bm + wm + mi * 16 + (lane >> 4) * 4 + q;
                if (r < M) {
                    atomicAdd(&asT[(size_t)head * M + r], ps);
                    atomicAdd(&adT[(size_t)head * M + r], pd);
                }
            }
        }
    }
}

// ---------------- channel-sliced softmax-aggregate, fp16 gather table -------
// R3 structure (NSLICE=4, fused softmax, LDS-staged metadata) with fp16 h:
// 16B lane-load covers 8 channels -> gather instructions halve, per-slice
// working set 2.5MB fits the 4MB XCD L2 (R11: FETCH 102->18MB, absmax
// unchanged). R11's fused pool REVERTED: 2.56M atomics on 8K gout addresses
// serialized the layer-3 dispatch to 366us (WRITE 90MB, VALUBusy 8.5%).
// pool_mean4 (32K atomics, ~5us) restored.

template <int SCH, int F, int HEADS, bool DO_ELU, bool SPLIT>
__global__ __launch_bounds__(256) void gat_aggregate6(
        const __half* __restrict__ h,     // [N, F] fp16
        const float* __restrict__ asT,    // [HEADS][N]
        const float* __restrict__ adT,    // [HEADS][N]
        const int* __restrict__ row_ptr,
        const int* __restrict__ col,
        const float* __restrict__ bias,   // [F]
        float* __restrict__ out,          // [N, F]   (SPLIT=false)
        unsigned short* __restrict__ oh,  // [N, F]   (SPLIT=true)
        unsigned short* __restrict__ ol) {
    constexpr int CL = SCH / 8;           // lanes per edge (8 or 4): 16B = 8 fp16
    constexpr int E  = 64 / CL;           // parallel edges (8 or 16)
    constexpr int CPH = F / HEADS;        // channels per head
    __shared__ int   s_off[4][64];
    __shared__ float s_p[4][64];
    int slice = blockIdx.x & 3;           // NSLICE == 4
    int ng = blockIdx.x >> 2;
    int wid = threadIdx.x >> 6, lane = threadIdx.x & 63;
    int v = ng * 4 + wid;
    if (v >= N_NODES) return;
    int head = (slice * SCH) / CPH;       // layers 1/2: slice; layer 3: 0
    int eg = lane / CL, cl = lane % CL;
    int r0 = row_ptr[v], r1 = row_ptr[v + 1];
    float ad = adT[head * N_NODES + v];
    const float* asrc = asT + head * N_NODES;
    float acc[8] = {};
    float lsum = 0.f;
    const char* hb = (const char*)h + (slice * SCH + cl * 8) * 2;

#define HFMA(pk, hw)                                                       \
    { const __half2* q2 = (const __half2*)&(hw);                           \
      float2 f0 = __half22float2(q2[0]);                                   \
      float2 f1 = __half22float2(q2[1]);                                   \
      float2 f2 = __half22float2(q2[2]);                                   \
      float2 f3 = __half22float2(q2[3]);                                   \
      acc[0] = fmaf(pk, f0.x, acc[0]); acc[1] = fmaf(pk, f0.y, acc[1]);    \
      acc[2] = fmaf(pk, f1.x, acc[2]); acc[3] = fmaf(pk, f1.y, acc[3]);    \
      acc[4] = fmaf(pk, f2.x, acc[4]); acc[5] = fmaf(pk, f2.y, acc[5]);    \
      acc[6] = fmaf(pk, f3.x, acc[6]); acc[7] = fmaf(pk, f3.y, acc[7]); }

#define GATHER4(gg)                                                        \
    {                                                                      \
        int k0 = ((gg) + 0) * E + eg;                                      \
        int k1 = ((gg) + 1) * E + eg;                                      \
        int k2 = ((gg) + 2) * E + eg;                                      \
        int k3 = ((gg) + 3) * E + eg;                                      \
        float p0 = s_p[wid][k0]; int o0 = s_off[wid][k0];                  \
        float p1 = s_p[wid][k1]; int o1 = s_off[wid][k1];                  \
        float p2 = s_p[wid][k2]; int o2 = s_off[wid][k2];                  \
        float p3 = s_p[wid][k3]; int o3 = s_off[wid][k3];                  \
        uint4 h0 = *(const uint4*)(hb + o0);                               \
        uint4 h1 = *(const uint4*)(hb + o1);                               \
        uint4 h2 = *(const uint4*)(hb + o2);                               \
        uint4 h3 = *(const uint4*)(hb + o3);                               \
        HFMA(p0, h0); HFMA(p1, h1); HFMA(p2, h2); HFMA(p3, h3);            \
    }

    for (int base = r0; base < r1; base += 64) {
        int j = base + lane;
        bool valid = j < r1;
        int s = col[valid ? j : r0];
        float e = asrc[s] + ad;
        e = (e > 0.f) ? e : NEG_SLOPE * e;
        float p = valid ? __expf(e) : 0.f;
        lsum += p;
        s_p[wid][lane] = p;
        s_off[wid][lane] = s * (F * 2);   // byte offset of fp16 row s
        // wave-synchronous: wid-private LDS rows, no barrier needed

        int nk = min(64, r1 - base);
        int nkg = (nk + E - 1) / E;       // <= 64/E groups (8 or 4)
        int g = 0;
        for (; g + 4 <= nkg; g += 4) GATHER4(g);
        if (g < nkg) GATHER4(g);          // ragged tail: pad groups have p==0
    }
#undef GATHER4
#undef HFMA

    // full-wave softmax denominator
    #pragma unroll
    for (int o = 32; o; o >>= 1) lsum += __shfl_xor(lsum, o);
    // reduce acc across edge groups (lanes differing in bits >= log2(CL))
    #pragma unroll
    for (int c = 0; c < 8; ++c) {
        #pragma unroll
        for (int o = CL; o < 64; o <<= 1) acc[c] += __shfl_xor(acc[c], o);
    }
    if (eg == 0) {
        float inv = 1.f / (lsum + 1e-16f);
        int ch0 = slice * SCH + cl * 8;
        float o8[8];
        #pragma unroll
        for (int c = 0; c < 8; ++c) {
            float o = acc[c] * inv + bias[ch0 + c];
            if (DO_ELU) o = (o > 0.f) ? o : expm1f(o);
            o8[c] = o;
        }
        if constexpr (SPLIT) {
            unsigned short hv[8], lv[8];
            #pragma unroll
            for (int c = 0; c < 8; ++c) {
                hv[c] = bf_hi(o8[c]);
                lv[c] = bf_hi(o8[c] - bf_f(hv[c]));
            }
            *(uint4*)&oh[(size_t)v * F + ch0] = *(const uint4*)hv;
            *(uint4*)&ol[(size_t)v * F + ch0] = *(const uint4*)lv;
        } else {
            *(float4*)&out[(size_t)v * F + ch0]     = *(const float4*)&o8[0];
            *(float4*)&out[(size_t)v * F + ch0 + 4] = *(const float4*)&o8[4];
        }
    }
}

// ---------------- global mean pool: 4-way row-split + atomic combine --------

__global__ void pool_mean4(const float* __restrict__ hout, const int* __restrict__ gstart,
                           float* __restrict__ gout) {
    int g = blockIdx.x;       // 64
    int q = blockIdx.y;       // 4 row-quarters
    int c = threadIdx.x;      // 128 channels
    int off = gstart[g], end = gstart[g + 1];
    float inv = 1.f / fmaxf((float)(end - off), 1.0f);
    float s = 0.f;
    for (int i = off + q; i < end; i += 4) s += hout[(size_t)i * 128 + c];
    atomicAdd(&gout[g * 128 + c], s * inv);
}

// ---------------- launch ----------------

static inline size_t align_up(size_t x, size_t a) { return (x + a - 1) & ~(a - 1); }

extern "C" void kernel_launch(void* const* d_in, const int* in_sizes, int n_in,
                              void* d_out, int out_size, void* d_ws, size_t ws_size,
                              hipStream_t stream) {
    const float* x   = (const float*)d_in[0];
    const int*   ei  = (const int*)d_in[1];
    const int*   bat = (const int*)d_in[2];
    const float* W1  = (const float*)d_in[3];
    const float* as1 = (const float*)d_in[4];
    const float* ad1 = (const float*)d_in[5];
    const float* b1  = (const float*)d_in[6];
    const float* W2  = (const float*)d_in[7];
    const float* as2 = (const float*)d_in[8];
    const float* ad2 = (const float*)d_in[9];
    const float* b2  = (const float*)d_in[10];
    const float* W3  = (const float*)d_in[11];
    const float* as3 = (const float*)d_in[12];
    const float* ad3 = (const float*)d_in[13];
    const float* b3  = (const float*)d_in[14];

    float* gout = (float*)d_out;                     // [G,128]
    float* hout = (float*)d_out + G_GRAPHS * 128;    // [N,128]

    char* w = (char*)d_ws;
    size_t o = 0;
    __half* bufA = (__half*)(w + o);         o = align_up(o + (size_t)N_NODES * 256 * 2, 256);
    unsigned short* Bh = (unsigned short*)(w + o); o = align_up(o + (size_t)N_NODES * 256 * 2, 256);
    unsigned short* Bl = (unsigned short*)(w + o); o = align_up(o + (size_t)N_NODES * 256 * 2, 256);
    unsigned short* xh = (unsigned short*)(w + o); o = align_up(o + (size_t)N_NODES * 128 * 2, 256);
    unsigned short* xl = (unsigned short*)(w + o); o = align_up(o + (size_t)N_NODES * 128 * 2, 256);
    unsigned short* Wt1h = (unsigned short*)(w + o); o = align_up(o + (size_t)256 * 128 * 2, 256);
    unsigned short* Wt1l = (unsigned short*)(w + o); o = align_up(o + (size_t)256 * 128 * 2, 256);
    unsigned short* Wt2h = (unsigned short*)(w + o); o = align_up(o + (size_t)256 * 256 * 2, 256);
    unsigned short* Wt2l = (unsigned short*)(w + o); o = align_up(o + (size_t)256 * 256 * 2, 256);
    unsigned short* Wt3h = (unsigned short*)(w + o); o = align_up(o + (size_t)128 * 256 * 2, 256);
    unsigned short* Wt3l = (unsigned short*)(w + o); o = align_up(o + (size_t)128 * 256 * 2, 256);
    // per-layer alpha buffers, CONTIGUOUS (zeroed as one 360000-f32 block)
    float* alpha = (float*)(w + o);
    float* asv1 = alpha;                  // [4][N]
    float* adv1 = alpha + 4 * N_NODES;    // [4][N]
    float* asv2 = alpha + 8 * N_NODES;    // [4][N]
    float* adv2 = alpha + 12 * N_NODES;   // [4][N]
    float* asv3 = alpha + 16 * N_NODES;   // [N]
    float* adv3 = alpha + 17 * N_NODES;   // [N]
    o = align_up(o + (size_t)18 * N_NODES * 4, 256);
    int* row_ptr = (int*)(w + o);  o = align_up(o + (size_t)(N_NODES + 1) * 4, 256);
    int* col     = (int*)(w + o);  o = align_up(o + (size_t)ET_EDGES * 4, 256);
    int* cnt     = (int*)(w + o);  o += (size_t)N_NODES * 4;        // cnt+cur contiguous
    int* cur     = (int*)(w + o);  o = align_up(o + (size_t)N_NODES * 4, 256);
    int* gstart  = (int*)(w + o);  o = align_up(o + (size_t)(G_GRAPHS + 1) * 4, 256);

    // ---- fused prep (splits + zeroing) + CSR build ----
    {
        int total = 640000 + 32768 + 65536 + 32768 + 10000 + 2048 + 90000;
        prep_split<<<(total + 255) / 256, 256, 0, stream>>>(
            x, W1, W2, W3, xh, xl, Wt1h, Wt1l, Wt2h, Wt2l, Wt3h, Wt3l, cnt, gout, alpha);
    }
    hist_dst<<<(ET_EDGES + 255) / 256, 256, 0, stream>>>(ei, cnt, bat, gstart);
    scan_rowptr<<<1, 1024, 0, stream>>>(cnt, row_ptr);
    fill_csr<<<(ET_EDGES + 255) / 256, 256, 0, stream>>>(ei, row_ptr, cur, col);

    int gm = (N_NODES + 127) / 128;   // 157
    int nb = (N_NODES + 3) / 4;       // 4 nodes per block
    int nbs = nb * 4;                 // x4 channel slices

    // ---- layer 1: 128 -> 4x64 (alpha fused into GEMM epilogue) ----
    gemm_split<64><<<dim3(gm, 4), 256, 0, stream>>>(
        xh, xl, Wt1h, Wt1l, bufA, N_NODES, 256, 128, as1, ad1, asv1, adv1);
    gat_aggregate6<64, 256, 4, true, true><<<nbs, 256, 0, stream>>>(
        bufA, asv1, adv1, row_ptr, col, b1, nullptr, Bh, Bl);

    // ---- layer 2: 256 -> 4x64 ----
    gemm_split<64><<<dim3(gm, 4), 256, 0, stream>>>(
        Bh, Bl, Wt2h, Wt2l, bufA, N_NODES, 256, 256, as2, ad2, asv2, adv2);
    gat_aggregate6<64, 256, 4, true, true><<<nbs, 256, 0, stream>>>(
        bufA, asv2, adv2, row_ptr, col, b2, nullptr, Bh, Bl);

    // ---- layer 3: 256 -> 128 (1 head) ----
    gemm_split<128><<<dim3(gm, 2), 256, 0, stream>>>(
        Bh, Bl, Wt3h, Wt3l, bufA, N_NODES, 128, 256, as3, ad3, asv3, adv3);
    gat_aggregate6<32, 128, 1, false, false><<<nbs, 256, 0, stream>>>(
        bufA, asv3, adv3, row_ptr, col, b3, hout, nullptr, nullptr);

    // ---- global mean pool ----
    pool_mean4<<<dim3(G_GRAPHS, 4), 128, 0, stream>>>(hout, gstart, gout);
}

// Round 13
// 418.568 us; speedup vs baseline: 1.6935x; 1.0605x over previous
//
#include <hip/hip_runtime.h>
#include <hip/hip_bf16.h>
#include <math.h>

#define N_NODES 20000
#define N_EDGES 640000
#define ET_EDGES (N_EDGES + N_NODES)   // with self-loops
#define G_GRAPHS 64
#define NEG_SLOPE 0.2f

typedef __attribute__((ext_vector_type(8))) short s8v;   // 8 bf16 (4 VGPR)
typedef __attribute__((ext_vector_type(4))) float f4v;   // 4 fp32 acc

// fp32 -> bf16 (RNE) and back
__device__ __forceinline__ unsigned short bf_hi(float f) {
    union { float f; unsigned int u; } c; c.f = f;
    unsigned int r = (c.u + 0x7fffu + ((c.u >> 16) & 1u)) >> 16;
    return (unsigned short)r;
}
__device__ __forceinline__ float bf_f(unsigned short h) {
    union { unsigned int u; float f; } c; c.u = ((unsigned int)h) << 16;
    return c.f;
}

// ---------------- CSR construction (+ graph bounds folded in) ----------------

__global__ void hist_dst(const int* __restrict__ ei, int* __restrict__ cnt,
                         const int* __restrict__ batch, int* __restrict__ gstart) {
    int j = blockIdx.x * blockDim.x + threadIdx.x;
    if (blockIdx.x == 0 && threadIdx.x <= G_GRAPHS) {
        int g = threadIdx.x;
        int lo = 0, hi = N_NODES;
        while (lo < hi) {              // first i with batch[i] >= g
            int mid = (lo + hi) >> 1;
            if (batch[mid] < g) lo = mid + 1; else hi = mid;
        }
        gstart[g] = lo;
    }
    if (j >= ET_EDGES) return;
    int d = (j < N_EDGES) ? ei[N_EDGES + j] : (j - N_EDGES);
    atomicAdd(&cnt[d], 1);
}

__global__ __launch_bounds__(1024) void scan_rowptr(const int* __restrict__ cnt,
                                                    int* __restrict__ row_ptr) {
    __shared__ int sums[1024];
    const int n = N_NODES;
    const int CH = (n + 1023) / 1024;   // 20
    int t = threadIdx.x;
    int base = t * CH;
    int s = 0;
    for (int i = 0; i < CH; ++i) {
        int idx = base + i;
        if (idx < n) s += cnt[idx];
    }
    sums[t] = s;
    __syncthreads();
    for (int o = 1; o < 1024; o <<= 1) {
        int v = (t >= o) ? sums[t - o] : 0;
        __syncthreads();
        sums[t] += v;
        __syncthreads();
    }
    int run = (t == 0) ? 0 : sums[t - 1];
    for (int i = 0; i < CH; ++i) {
        int idx = base + i;
        if (idx < n) { row_ptr[idx] = run; run += cnt[idx]; }
    }
    if (t == 1023) row_ptr[n] = sums[1023];
}

__global__ void fill_csr(const int* __restrict__ ei, const int* __restrict__ row_ptr,
                         int* __restrict__ cur, int* __restrict__ col) {
    int j = blockIdx.x * blockDim.x + threadIdx.x;
    if (j >= ET_EDGES) return;
    int s, d;
    if (j < N_EDGES) { s = ei[j]; d = ei[N_EDGES + j]; }
    else             { s = d = j - N_EDGES; }
    int pos = row_ptr[d] + atomicAdd(&cur[d], 1);
    col[pos] = s;
}

// ---------------- fused prep: x/W splits + buffer zeroing -------------------
// Zeroes cnt+cur, gout, and the LAYER-3 alpha accumulators only (40000 f32;
// layers 1/2 alpha is now direct-stored by the 128-wide GEMM epilogue).

__global__ void prep_split(const float* __restrict__ x,
                           const float* __restrict__ W1, const float* __restrict__ W2,
                           const float* __restrict__ W3,
                           unsigned short* __restrict__ xh, unsigned short* __restrict__ xl,
                           unsigned short* __restrict__ w1h, unsigned short* __restrict__ w1l,
                           unsigned short* __restrict__ w2h, unsigned short* __restrict__ w2l,
                           unsigned short* __restrict__ w3h, unsigned short* __restrict__ w3l,
                           int* __restrict__ cntcur, float* __restrict__ gout,
                           float* __restrict__ a3z) {
    int idx = blockIdx.x * blockDim.x + threadIdx.x;
    if (idx < 640000) {                     // x: [20000*128] f32 -> hi/lo, vec4
        int i = idx * 4;
        float4 v = *(const float4*)&x[i];
        ushort4 h, l;
        h.x = bf_hi(v.x); l.x = bf_hi(v.x - bf_f(h.x));
        h.y = bf_hi(v.y); l.y = bf_hi(v.y - bf_f(h.y));
        h.z = bf_hi(v.z); l.z = bf_hi(v.z - bf_f(h.z));
        h.w = bf_hi(v.w); l.w = bf_hi(v.w - bf_f(h.w));
        *(ushort4*)&xh[i] = h;
        *(ushort4*)&xl[i] = l;
        return;
    }
    idx -= 640000;
    if (idx < 32768) {                      // W1 [128][256] -> [256][128]
        int k = idx / 256, n = idx % 256;
        float v = W1[idx];
        unsigned short h = bf_hi(v);
        w1h[n * 128 + k] = h;
        w1l[n * 128 + k] = bf_hi(v - bf_f(h));
        return;
    }
    idx -= 32768;
    if (idx < 65536) {                      // W2 [256][256] -> [256][256]
        int k = idx / 256, n = idx % 256;
        float v = W2[idx];
        unsigned short h = bf_hi(v);
        w2h[n * 256 + k] = h;
        w2l[n * 256 + k] = bf_hi(v - bf_f(h));
        return;
    }
    idx -= 65536;
    if (idx < 32768) {                      // W3 [256][128] -> [128][256]
        int k = idx / 128, n = idx % 128;
        float v = W3[idx];
        unsigned short h = bf_hi(v);
        w3h[n * 256 + k] = h;
        w3l[n * 256 + k] = bf_hi(v - bf_f(h));
        return;
    }
    idx -= 32768;
    if (idx < 10000) {                      // zero cnt+cur (40000 ints, vec4)
        *(int4*)&cntcur[idx * 4] = make_int4(0, 0, 0, 0);
        return;
    }
    idx -= 10000;
    if (idx < 2048) {                       // zero gout (8192 floats, vec4)
        *(float4*)&gout[idx * 4] = make_float4(0.f, 0.f, 0.f, 0.f);
        return;
    }
    idx -= 2048;
    if (idx < 10000) {                      // zero asv3+adv3 (40000 f32, vec4)
        *(float4*)&a3z[idx * 4] = make_float4(0.f, 0.f, 0.f, 0.f);
    }
}

// ---------------- split-bf16 MFMA GEMM, 128x128 tile + fused alpha ----------
// C = Ah*Bh + Ah*Bl + Al*Bh (lo*lo ~2^-18 rel, dropped). fp32 accumulate.
// R13: tile 128x128, 4 waves of 64x64 (48 MFMA per 32-K step, 2x the old
// 128x64 tile's amortization of barriers+staging). Each wave's 64 columns
// cover exactly ONE head when CPH=64 -> alpha epilogue direct-stores the
// complete head dot (no atomics; R9's race is structurally impossible since
// the wave reduces all 4 nj fragments = all 64 head columns). CPH=128
// (layer 3): wave covers half the head -> atomicAdd into pre-zeroed bufs.

#define LDT 40

template <int CPH>
__global__ __launch_bounds__(256) void gemm_split(
        const unsigned short* __restrict__ Ah, const unsigned short* __restrict__ Al,
        const unsigned short* __restrict__ Bh, const unsigned short* __restrict__ Bl,
        float* __restrict__ C, int M, int Nc, int K,
        const float* __restrict__ a_src, const float* __restrict__ a_dst,
        float* __restrict__ asT, float* __restrict__ adT) {
    __shared__ unsigned short lAh[128 * LDT];
    __shared__ unsigned short lAl[128 * LDT];
    __shared__ unsigned short lBh[128 * LDT];
    __shared__ unsigned short lBl[128 * LDT];
    int bm = blockIdx.x * 128, bn = blockIdx.y * 128;
    int t = threadIdx.x, w = t >> 6, lane = t & 63;
    int wm = (w >> 1) * 64, wn = (w & 1) * 64;

    f4v acc[4][4] = {};

    // staging: A and B each 128 rows x 32 k, hi+lo; 16 ushort/thread each
    int sr = t >> 1, sk = (t & 1) << 4;
    int ar = bm + sr; if (ar >= M) ar = M - 1;
    const unsigned short* pAh = Ah + (size_t)ar * K + sk;
    const unsigned short* pAl = Al + (size_t)ar * K + sk;
    const unsigned short* pBh = Bh + (size_t)(bn + sr) * K + sk;
    const unsigned short* pBl = Bl + (size_t)(bn + sr) * K + sk;

    int fr = lane & 15, fk = (lane >> 4) << 3;

    for (int k0 = 0; k0 < K; k0 += 32) {
        uint4 vh0 = *(const uint4*)(pAh + k0);
        uint4 vh1 = *(const uint4*)(pAh + k0 + 8);
        uint4 vl0 = *(const uint4*)(pAl + k0);
        uint4 vl1 = *(const uint4*)(pAl + k0 + 8);
        uint4 wh0 = *(const uint4*)(pBh + k0);
        uint4 wh1 = *(const uint4*)(pBh + k0 + 8);
        uint4 wl0 = *(const uint4*)(pBl + k0);
        uint4 wl1 = *(const uint4*)(pBl + k0 + 8);
        __syncthreads();
        *(uint4*)&lAh[sr * LDT + sk]     = vh0;
        *(uint4*)&lAh[sr * LDT + sk + 8] = vh1;
        *(uint4*)&lAl[sr * LDT + sk]     = vl0;
        *(uint4*)&lAl[sr * LDT + sk + 8] = vl1;
        *(uint4*)&lBh[sr * LDT + sk]     = wh0;
        *(uint4*)&lBh[sr * LDT + sk + 8] = wh1;
        *(uint4*)&lBl[sr * LDT + sk]     = wl0;
        *(uint4*)&lBl[sr * LDT + sk + 8] = wl1;
        __syncthreads();

        s8v a_h[4], a_l[4], b_h[4], b_l[4];
        #pragma unroll
        for (int mi = 0; mi < 4; ++mi) {
            a_h[mi] = *(const s8v*)&lAh[(wm + mi * 16 + fr) * LDT + fk];
            a_l[mi] = *(const s8v*)&lAl[(wm + mi * 16 + fr) * LDT + fk];
        }
        #pragma unroll
        for (int nj = 0; nj < 4; ++nj) {
            b_h[nj] = *(const s8v*)&lBh[(wn + nj * 16 + fr) * LDT + fk];
            b_l[nj] = *(const s8v*)&lBl[(wn + nj * 16 + fr) * LDT + fk];
        }
        #pragma unroll
        for (int mi = 0; mi < 4; ++mi)
            #pragma unroll
            for (int nj = 0; nj < 4; ++nj) {
                acc[mi][nj] = __builtin_amdgcn_mfma_f32_16x16x32_bf16(
                    a_h[mi], b_h[nj], acc[mi][nj], 0, 0, 0);
                acc[mi][nj] = __builtin_amdgcn_mfma_f32_16x16x32_bf16(
                    a_h[mi], b_l[nj], acc[mi][nj], 0, 0, 0);
                acc[mi][nj] = __builtin_amdgcn_mfma_f32_16x16x32_bf16(
                    a_l[mi], b_h[nj], acc[mi][nj], 0, 0, 0);
            }
    }

    // C/D layout: col = lane&15, row = (lane>>4)*4 + q  [verified gfx950]
    #pragma unroll
    for (int mi = 0; mi < 4; ++mi)
        #pragma unroll
        for (int nj = 0; nj < 4; ++nj) {
            int row0 = bm + wm + mi * 16 + (lane >> 4) * 4;
            int colc = bn + wn + nj * 16 + (lane & 15);
            #pragma unroll
            for (int q = 0; q < 4; ++q) {
                int r = row0 + q;
                if (r < M) C[(size_t)r * Nc + colc] = acc[mi][nj][q];
            }
        }

    // ---- fused alpha epilogue ----
    // Wave covers cols [bn+wn, bn+wn+64) = full head if CPH==64.
    float av_s[4], av_d[4];
    #pragma unroll
    for (int nj = 0; nj < 4; ++nj) {
        int aidx = bn + wn + nj * 16 + fr;
        av_s[nj] = a_src[aidx];
        av_d[nj] = a_dst[aidx];
    }
    int head = (bn + wn) / CPH;
    #pragma unroll
    for (int mi = 0; mi < 4; ++mi) {
        #pragma unroll
        for (int q = 0; q < 4; ++q) {
            float ps = acc[mi][0][q] * av_s[0] + acc[mi][1][q] * av_s[1]
                     + acc[mi][2][q] * av_s[2] + acc[mi][3][q] * av_s[3];
            float pd = acc[mi][0][q] * av_d[0] + acc[mi][1][q] * av_d[1]
                     + acc[mi][2][q] * av_d[2] + acc[mi][3][q] * av_d[3];
            #pragma unroll
            for (int o = 1; o < 16; o <<= 1) {
                ps += __shfl_xor(ps, o);
                pd += __shfl_xor(pd, o);
            }
            if (fr == 0) {
                int r = bm + wm + mi * 16 + (lane >> 4) * 4 + q;
                if (r < M) {
                    if (CPH == 64) {          // wave == full head: direct store
                        asT[(size_t)head * M + r] = ps;
                        adT[(size_t)head * M + r] = pd;
                    } else {                  // half head: atomic combine
                        atomicAdd(&asT[r], ps);
                        atomicAdd(&adT[r], pd);
                    }
                }
            }
        }
    }
}

// ---------------- channel-sliced softmax-aggregate (R10-measured optimum) ---
// NSLICE=4, fused softmax, fp32 table, GATHER4, VGPR 28 — every probed
// perturbation (NSLICE 1/8, unroll 8, precomputed pex, fp16 table) lost.

template <int NSLICE, int SCH, int F, int HEADS, bool DO_ELU, bool SPLIT>
__global__ __launch_bounds__(256) void gat_aggregate_sliced(
        const float* __restrict__ h,      // [N, F]
        const float* __restrict__ asT,    // [HEADS][N]
        const float* __restrict__ adT,    // [HEADS][N]
        const int* __restrict__ row_ptr,
        const int* __restrict__ col,
        const float* __restrict__ bias,   // [F]
        float* __restrict__ out,          // [N, F]   (SPLIT=false)
        unsigned short* __restrict__ oh,  // [N, F]   (SPLIT=true)
        unsigned short* __restrict__ ol) {
    constexpr int CL = SCH / 4;           // lanes per edge (16 or 8)
    constexpr int E  = 64 / CL;           // parallel edges (4 or 8)
    constexpr int CPH = F / HEADS;        // channels per head
    __shared__ int   s_off[4][64];
    __shared__ float s_p[4][64];
    int slice = blockIdx.x & (NSLICE - 1);
    int ng = blockIdx.x >> 2;             // NSLICE == 4
    int wid = threadIdx.x >> 6, lane = threadIdx.x & 63;
    int v = ng * 4 + wid;
    if (v >= N_NODES) return;
    int head = (slice * SCH) / CPH;       // layers 1/2: slice == head; layer 3: 0
    int eg = lane / CL, cl = lane % CL;
    int r0 = row_ptr[v], r1 = row_ptr[v + 1];
    float ad = adT[head * N_NODES + v];
    const float* asrc = asT + head * N_NODES;
    float acc[4] = {};
    float lsum = 0.f;
    const char* hb = (const char*)(h + slice * SCH + cl * 4);

#define GATHER4(gg)                                                        \
    {                                                                      \
        int k0 = ((gg) + 0) * E + eg;                                      \
        int k1 = ((gg) + 1) * E + eg;                                      \
        int k2 = ((gg) + 2) * E + eg;                                      \
        int k3 = ((gg) + 3) * E + eg;                                      \
        float p0 = s_p[wid][k0]; int o0 = s_off[wid][k0];                  \
        float p1 = s_p[wid][k1]; int o1 = s_off[wid][k1];                  \
        float p2 = s_p[wid][k2]; int o2 = s_off[wid][k2];                  \
        float p3 = s_p[wid][k3]; int o3 = s_off[wid][k3];                  \
        float4 h0 = *(const float4*)(hb + o0);                             \
        float4 h1 = *(const float4*)(hb + o1);                             \
        float4 h2 = *(const float4*)(hb + o2);                             \
        float4 h3 = *(const float4*)(hb + o3);                             \
        acc[0] = fmaf(p0, h0.x, acc[0]);                                   \
        acc[1] = fmaf(p0, h0.y, acc[1]);                                   \
        acc[2] = fmaf(p0, h0.z, acc[2]);                                   \
        acc[3] = fmaf(p0, h0.w, acc[3]);                                   \
        acc[0] = fmaf(p1, h1.x, acc[0]);                                   \
        acc[1] = fmaf(p1, h1.y, acc[1]);                                   \
        acc[2] = fmaf(p1, h1.z, acc[2]);                                   \
        acc[3] = fmaf(p1, h1.w, acc[3]);                                   \
        acc[0] = fmaf(p2, h2.x, acc[0]);                                   \
        acc[1] = fmaf(p2, h2.y, acc[1]);                                   \
        acc[2] = fmaf(p2, h2.z, acc[2]);                                   \
        acc[3] = fmaf(p2, h2.w, acc[3]);                                   \
        acc[0] = fmaf(p3, h3.x, acc[0]);                                   \
        acc[1] = fmaf(p3, h3.y, acc[1]);                                   \
        acc[2] = fmaf(p3, h3.z, acc[2]);                                   \
        acc[3] = fmaf(p3, h3.w, acc[3]);                                   \
    }

    for (int base = r0; base < r1; base += 64) {
        int j = base + lane;
        bool valid = j < r1;
        int s = col[valid ? j : r0];
        float e = asrc[s] + ad;
        e = (e > 0.f) ? e : NEG_SLOPE * e;
        float p = valid ? __expf(e) : 0.f;
        lsum += p;
        s_p[wid][lane] = p;
        s_off[wid][lane] = s * (F * 4);   // byte offset of row s

        int nk = min(64, r1 - base);
        int nkg = (nk + E - 1) / E;       // <= 64/E
        int g = 0;
        for (; g + 4 <= nkg; g += 4) GATHER4(g);
        if (g < nkg) GATHER4(g);          // ragged tail: extra groups have p==0
    }
#undef GATHER4

    // full-wave softmax denominator
    #pragma unroll
    for (int o = 32; o; o >>= 1) lsum += __shfl_xor(lsum, o);
    // reduce acc across edge groups (lanes differing in bits >= log2(CL))
    #pragma unroll
    for (int c = 0; c < 4; ++c) {
        #pragma unroll
        for (int o = CL; o < 64; o <<= 1) acc[c] += __shfl_xor(acc[c], o);
    }
    if (eg == 0) {
        float inv = 1.f / (lsum + 1e-16f);
        int ch0 = slice * SCH + cl * 4;
        float o4[4];
        #pragma unroll
        for (int c = 0; c < 4; ++c) {
            float o = acc[c] * inv + bias[ch0 + c];
            if (DO_ELU) o = (o > 0.f) ? o : expm1f(o);
            o4[c] = o;
        }
        if constexpr (SPLIT) {
            ushort4 hv4, lv4;
            hv4.x = bf_hi(o4[0]); lv4.x = bf_hi(o4[0] - bf_f(hv4.x));
            hv4.y = bf_hi(o4[1]); lv4.y = bf_hi(o4[1] - bf_f(hv4.y));
            hv4.z = bf_hi(o4[2]); lv4.z = bf_hi(o4[2] - bf_f(hv4.z));
            hv4.w = bf_hi(o4[3]); lv4.w = bf_hi(o4[3] - bf_f(hv4.w));
            *(ushort4*)&oh[(size_t)v * F + ch0] = hv4;
            *(ushort4*)&ol[(size_t)v * F + ch0] = lv4;
        } else {
            *(float4*)&out[(size_t)v * F + ch0] =
                make_float4(o4[0], o4[1], o4[2], o4[3]);
        }
    }
}

// ---------------- global mean pool: 4-way row-split + atomic combine --------

__global__ void pool_mean4(const float* __restrict__ hout, const int* __restrict__ gstart,
                           float* __restrict__ gout) {
    int g = blockIdx.x;       // 64
    int q = blockIdx.y;       // 4 row-quarters
    int c = threadIdx.x;      // 128 channels
    int off = gstart[g], end = gstart[g + 1];
    float inv = 1.f / fmaxf((float)(end - off), 1.0f);
    float s = 0.f;
    for (int i = off + q; i < end; i += 4) s += hout[(size_t)i * 128 + c];
    atomicAdd(&gout[g * 128 + c], s * inv);
}

// ---------------- launch ----------------

static inline size_t align_up(size_t x, size_t a) { return (x + a - 1) & ~(a - 1); }

extern "C" void kernel_launch(void* const* d_in, const int* in_sizes, int n_in,
                              void* d_out, int out_size, void* d_ws, size_t ws_size,
                              hipStream_t stream) {
    const float* x   = (const float*)d_in[0];
    const int*   ei  = (const int*)d_in[1];
    const int*   bat = (const int*)d_in[2];
    const float* W1  = (const float*)d_in[3];
    const float* as1 = (const float*)d_in[4];
    const float* ad1 = (const float*)d_in[5];
    const float* b1  = (const float*)d_in[6];
    const float* W2  = (const float*)d_in[7];
    const float* as2 = (const float*)d_in[8];
    const float* ad2 = (const float*)d_in[9];
    const float* b2  = (const float*)d_in[10];
    const float* W3  = (const float*)d_in[11];
    const float* as3 = (const float*)d_in[12];
    const float* ad3 = (const float*)d_in[13];
    const float* b3  = (const float*)d_in[14];

    float* gout = (float*)d_out;                     // [G,128]
    float* hout = (float*)d_out + G_GRAPHS * 128;    // [N,128]

    char* w = (char*)d_ws;
    size_t o = 0;
    float* bufA = (float*)(w + o);           o = align_up(o + (size_t)N_NODES * 256 * 4, 256);
    unsigned short* Bh = (unsigned short*)(w + o); o = align_up(o + (size_t)N_NODES * 256 * 2, 256);
    unsigned short* Bl = (unsigned short*)(w + o); o = align_up(o + (size_t)N_NODES * 256 * 2, 256);
    unsigned short* xh = (unsigned short*)(w + o); o = align_up(o + (size_t)N_NODES * 128 * 2, 256);
    unsigned short* xl = (unsigned short*)(w + o); o = align_up(o + (size_t)N_NODES * 128 * 2, 256);
    unsigned short* Wt1h = (unsigned short*)(w + o); o = align_up(o + (size_t)256 * 128 * 2, 256);
    unsigned short* Wt1l = (unsigned short*)(w + o); o = align_up(o + (size_t)256 * 128 * 2, 256);
    unsigned short* Wt2h = (unsigned short*)(w + o); o = align_up(o + (size_t)256 * 256 * 2, 256);
    unsigned short* Wt2l = (unsigned short*)(w + o); o = align_up(o + (size_t)256 * 256 * 2, 256);
    unsigned short* Wt3h = (unsigned short*)(w + o); o = align_up(o + (size_t)128 * 256 * 2, 256);
    unsigned short* Wt3l = (unsigned short*)(w + o); o = align_up(o + (size_t)128 * 256 * 2, 256);
    // per-layer alpha buffers (only asv3/adv3 need pre-zeroing)
    float* alpha = (float*)(w + o);
    float* asv1 = alpha;                  // [4][N]
    float* adv1 = alpha + 4 * N_NODES;    // [4][N]
    float* asv2 = alpha + 8 * N_NODES;    // [4][N]
    float* adv2 = alpha + 12 * N_NODES;   // [4][N]
    float* asv3 = alpha + 16 * N_NODES;   // [N]
    float* adv3 = alpha + 17 * N_NODES;   // [N]
    o = align_up(o + (size_t)18 * N_NODES * 4, 256);
    int* row_ptr = (int*)(w + o);  o = align_up(o + (size_t)(N_NODES + 1) * 4, 256);
    int* col     = (int*)(w + o);  o = align_up(o + (size_t)ET_EDGES * 4, 256);
    int* cnt     = (int*)(w + o);  o += (size_t)N_NODES * 4;        // cnt+cur contiguous
    int* cur     = (int*)(w + o);  o = align_up(o + (size_t)N_NODES * 4, 256);
    int* gstart  = (int*)(w + o);  o = align_up(o + (size_t)(G_GRAPHS + 1) * 4, 256);

    // ---- fused prep (splits + zeroing) + CSR build ----
    {
        int total = 640000 + 32768 + 65536 + 32768 + 10000 + 2048 + 10000;
        prep_split<<<(total + 255) / 256, 256, 0, stream>>>(
            x, W1, W2, W3, xh, xl, Wt1h, Wt1l, Wt2h, Wt2l, Wt3h, Wt3l, cnt, gout, asv3);
    }
    hist_dst<<<(ET_EDGES + 255) / 256, 256, 0, stream>>>(ei, cnt, bat, gstart);
    scan_rowptr<<<1, 1024, 0, stream>>>(cnt, row_ptr);
    fill_csr<<<(ET_EDGES + 255) / 256, 256, 0, stream>>>(ei, row_ptr, cur, col);

    int gm = (N_NODES + 127) / 128;   // 157
    int nb = (N_NODES + 3) / 4;       // 4 nodes per block
    int nbs = nb * 4;                 // x4 channel slices

    // ---- layer 1: 128 -> 4x64 (alpha fused into GEMM epilogue) ----
    gemm_split<64><<<dim3(gm, 2), 256, 0, stream>>>(
        xh, xl, Wt1h, Wt1l, bufA, N_NODES, 256, 128, as1, ad1, asv1, adv1);
    gat_aggregate_sliced<4, 64, 256, 4, true, true><<<nbs, 256, 0, stream>>>(
        bufA, asv1, adv1, row_ptr, col, b1, nullptr, Bh, Bl);

    // ---- layer 2: 256 -> 4x64 ----
    gemm_split<64><<<dim3(gm, 2), 256, 0, stream>>>(
        Bh, Bl, Wt2h, Wt2l, bufA, N_NODES, 256, 256, as2, ad2, asv2, adv2);
    gat_aggregate_sliced<4, 64, 256, 4, true, true><<<nbs, 256, 0, stream>>>(
        bufA, asv2, adv2, row_ptr, col, b2, nullptr, Bh, Bl);

    // ---- layer 3: 256 -> 128 (1 head; half-head waves -> atomics) ----
    gemm_split<128><<<dim3(gm, 1), 256, 0, stream>>>(
        Bh, Bl, Wt3h, Wt3l, bufA, N_NODES, 128, 256, as3, ad3, asv3, adv3);
    gat_aggregate_sliced<4, 32, 128, 1, false, false><<<nbs, 256, 0, stream>>>(
        bufA, asv3, adv3, row_ptr, col, b3, hout, nullptr, nullptr);

    // ---- global mean pool ----
    pool_mean4<<<dim3(G_GRAPHS, 4), 128, 0, stream>>>(hout, gstart, gout);
}

// Round 14
// 398.068 us; speedup vs baseline: 1.7807x; 1.0515x over previous
//
#include <hip/hip_runtime.h>
#include <hip/hip_bf16.h>
#include <math.h>

#define N_NODES 20000
#define N_EDGES 640000
#define ET_EDGES (N_EDGES + N_NODES)   // with self-loops
#define G_GRAPHS 64
#define NEG_SLOPE 0.2f

typedef __attribute__((ext_vector_type(8))) short s8v;   // 8 bf16 (4 VGPR)
typedef __attribute__((ext_vector_type(4))) float f4v;   // 4 fp32 acc

// fp32 -> bf16 (RNE) and back
__device__ __forceinline__ unsigned short bf_hi(float f) {
    union { float f; unsigned int u; } c; c.f = f;
    unsigned int r = (c.u + 0x7fffu + ((c.u >> 16) & 1u)) >> 16;
    return (unsigned short)r;
}
__device__ __forceinline__ float bf_f(unsigned short h) {
    union { unsigned int u; float f; } c; c.u = ((unsigned int)h) << 16;
    return c.f;
}

// ---------------- CSR construction (+ graph bounds folded in) ----------------

__global__ void hist_dst(const int* __restrict__ ei, int* __restrict__ cnt,
                         const int* __restrict__ batch, int* __restrict__ gstart) {
    int j = blockIdx.x * blockDim.x + threadIdx.x;
    if (blockIdx.x == 0 && threadIdx.x <= G_GRAPHS) {
        int g = threadIdx.x;
        int lo = 0, hi = N_NODES;
        while (lo < hi) {              // first i with batch[i] >= g
            int mid = (lo + hi) >> 1;
            if (batch[mid] < g) lo = mid + 1; else hi = mid;
        }
        gstart[g] = lo;
    }
    if (j >= ET_EDGES) return;
    int d = (j < N_EDGES) ? ei[N_EDGES + j] : (j - N_EDGES);
    atomicAdd(&cnt[d], 1);
}

// R14: all loads/stores staged through LDS coalesced (old version did
// stride-20 uncoalesced global reads -> ~80 lines/wave/round on ONE CU).
__global__ __launch_bounds__(1024) void scan_rowptr(const int* __restrict__ cnt,
                                                    int* __restrict__ row_ptr) {
    __shared__ int lds[N_NODES];      // 80 KB
    __shared__ int sums[1024];
    const int n = N_NODES;
    const int CH = (n + 1023) / 1024;   // 20
    int t = threadIdx.x;
    for (int i = t; i < n; i += 1024) lds[i] = cnt[i];
    __syncthreads();
    int base = t * CH;
    int s = 0;
    for (int i = 0; i < CH; ++i) {
        int idx = base + i;
        if (idx < n) s += lds[idx];
    }
    sums[t] = s;
    __syncthreads();
    for (int o = 1; o < 1024; o <<= 1) {
        int v = (t >= o) ? sums[t - o] : 0;
        __syncthreads();
        sums[t] += v;
        __syncthreads();
    }
    int run = (t == 0) ? 0 : sums[t - 1];
    for (int i = 0; i < CH; ++i) {
        int idx = base + i;
        if (idx < n) { int c = lds[idx]; lds[idx] = run; run += c; }
    }
    __syncthreads();
    for (int i = t; i < n; i += 1024) row_ptr[i] = lds[i];
    if (t == 1023) row_ptr[n] = sums[1023];
}

__global__ void fill_csr(const int* __restrict__ ei, const int* __restrict__ row_ptr,
                         int* __restrict__ cur, int* __restrict__ col) {
    int j = blockIdx.x * blockDim.x + threadIdx.x;
    if (j >= ET_EDGES) return;
    int s, d;
    if (j < N_EDGES) { s = ei[j]; d = ei[N_EDGES + j]; }
    else             { s = d = j - N_EDGES; }
    int pos = row_ptr[d] + atomicAdd(&cur[d], 1);
    col[pos] = s;
}

// ---------------- fused prep: x/W splits + buffer zeroing -------------------
// Zeroes cnt+cur, gout, and the LAYER-3 alpha accumulators only (40000 f32;
// layers 1/2 alpha is direct-stored by the 128-wide GEMM epilogue).

__global__ void prep_split(const float* __restrict__ x,
                           const float* __restrict__ W1, const float* __restrict__ W2,
                           const float* __restrict__ W3,
                           unsigned short* __restrict__ xh, unsigned short* __restrict__ xl,
                           unsigned short* __restrict__ w1h, unsigned short* __restrict__ w1l,
                           unsigned short* __restrict__ w2h, unsigned short* __restrict__ w2l,
                           unsigned short* __restrict__ w3h, unsigned short* __restrict__ w3l,
                           int* __restrict__ cntcur, float* __restrict__ gout,
                           float* __restrict__ a3z) {
    int idx = blockIdx.x * blockDim.x + threadIdx.x;
    if (idx < 640000) {                     // x: [20000*128] f32 -> hi/lo, vec4
        int i = idx * 4;
        float4 v = *(const float4*)&x[i];
        ushort4 h, l;
        h.x = bf_hi(v.x); l.x = bf_hi(v.x - bf_f(h.x));
        h.y = bf_hi(v.y); l.y = bf_hi(v.y - bf_f(h.y));
        h.z = bf_hi(v.z); l.z = bf_hi(v.z - bf_f(h.z));
        h.w = bf_hi(v.w); l.w = bf_hi(v.w - bf_f(h.w));
        *(ushort4*)&xh[i] = h;
        *(ushort4*)&xl[i] = l;
        return;
    }
    idx -= 640000;
    if (idx < 32768) {                      // W1 [128][256] -> [256][128]
        int k = idx / 256, n = idx % 256;
        float v = W1[idx];
        unsigned short h = bf_hi(v);
        w1h[n * 128 + k] = h;
        w1l[n * 128 + k] = bf_hi(v - bf_f(h));
        return;
    }
    idx -= 32768;
    if (idx < 65536) {                      // W2 [256][256] -> [256][256]
        int k = idx / 256, n = idx % 256;
        float v = W2[idx];
        unsigned short h = bf_hi(v);
        w2h[n * 256 + k] = h;
        w2l[n * 256 + k] = bf_hi(v - bf_f(h));
        return;
    }
    idx -= 65536;
    if (idx < 32768) {                      // W3 [256][128] -> [128][256]
        int k = idx / 128, n = idx % 128;
        float v = W3[idx];
        unsigned short h = bf_hi(v);
        w3h[n * 256 + k] = h;
        w3l[n * 256 + k] = bf_hi(v - bf_f(h));
        return;
    }
    idx -= 32768;
    if (idx < 10000) {                      // zero cnt+cur (40000 ints, vec4)
        *(int4*)&cntcur[idx * 4] = make_int4(0, 0, 0, 0);
        return;
    }
    idx -= 10000;
    if (idx < 2048) {                       // zero gout (8192 floats, vec4)
        *(float4*)&gout[idx * 4] = make_float4(0.f, 0.f, 0.f, 0.f);
        return;
    }
    idx -= 2048;
    if (idx < 10000) {                      // zero asv3+adv3 (40000 f32, vec4)
        *(float4*)&a3z[idx * 4] = make_float4(0.f, 0.f, 0.f, 0.f);
    }
}

// ---------------- split-bf16 MFMA GEMM, 128x128 tile + fused alpha ----------
// C = Ah*Bh + Ah*Bl + Al*Bh (lo*lo ~2^-18 rel, dropped). fp32 accumulate.
// Tile 128x128, 4 waves of 64x64 (48 MFMA per 32-K step). R14: REGISTER
// PREFETCH — next K-tile's 8 global loads are issued right after the LDS
// write barrier, BEFORE the MFMA block, so HBM latency hides under compute
// (old loop serialized load(k+1) after compute(k)). Barriers unchanged.
// Alpha epilogue: CPH=64 -> wave covers a full head, direct store; CPH=128
// (layer 3) -> half head, atomicAdd into pre-zeroed bufs (R10 fix).

#define LDT 40

template <int CPH>
__global__ __launch_bounds__(256) void gemm_split(
        const unsigned short* __restrict__ Ah, const unsigned short* __restrict__ Al,
        const unsigned short* __restrict__ Bh, const unsigned short* __restrict__ Bl,
        float* __restrict__ C, int M, int Nc, int K,
        const float* __restrict__ a_src, const float* __restrict__ a_dst,
        float* __restrict__ asT, float* __restrict__ adT) {
    __shared__ unsigned short lAh[128 * LDT];
    __shared__ unsigned short lAl[128 * LDT];
    __shared__ unsigned short lBh[128 * LDT];
    __shared__ unsigned short lBl[128 * LDT];
    int bm = blockIdx.x * 128, bn = blockIdx.y * 128;
    int t = threadIdx.x, w = t >> 6, lane = t & 63;
    int wm = (w >> 1) * 64, wn = (w & 1) * 64;

    f4v acc[4][4] = {};

    // staging: A and B each 128 rows x 32 k, hi+lo; 16 ushort/thread each
    int sr = t >> 1, sk = (t & 1) << 4;
    int ar = bm + sr; if (ar >= M) ar = M - 1;
    const unsigned short* pAh = Ah + (size_t)ar * K + sk;
    const unsigned short* pAl = Al + (size_t)ar * K + sk;
    const unsigned short* pBh = Bh + (size_t)(bn + sr) * K + sk;
    const unsigned short* pBl = Bl + (size_t)(bn + sr) * K + sk;

    int fr = lane & 15, fk = (lane >> 4) << 3;

    // preload K-tile 0
    uint4 vh0 = *(const uint4*)(pAh + 0);
    uint4 vh1 = *(const uint4*)(pAh + 8);
    uint4 vl0 = *(const uint4*)(pAl + 0);
    uint4 vl1 = *(const uint4*)(pAl + 8);
    uint4 wh0 = *(const uint4*)(pBh + 0);
    uint4 wh1 = *(const uint4*)(pBh + 8);
    uint4 wl0 = *(const uint4*)(pBl + 0);
    uint4 wl1 = *(const uint4*)(pBl + 8);

    for (int k0 = 0; k0 < K; k0 += 32) {
        __syncthreads();
        *(uint4*)&lAh[sr * LDT + sk]     = vh0;
        *(uint4*)&lAh[sr * LDT + sk + 8] = vh1;
        *(uint4*)&lAl[sr * LDT + sk]     = vl0;
        *(uint4*)&lAl[sr * LDT + sk + 8] = vl1;
        *(uint4*)&lBh[sr * LDT + sk]     = wh0;
        *(uint4*)&lBh[sr * LDT + sk + 8] = wh1;
        *(uint4*)&lBl[sr * LDT + sk]     = wl0;
        *(uint4*)&lBl[sr * LDT + sk + 8] = wl1;
        __syncthreads();

        int kn = k0 + 32;
        if (kn < K) {                      // prefetch next tile (hides HBM)
            vh0 = *(const uint4*)(pAh + kn);
            vh1 = *(const uint4*)(pAh + kn + 8);
            vl0 = *(const uint4*)(pAl + kn);
            vl1 = *(const uint4*)(pAl + kn + 8);
            wh0 = *(const uint4*)(pBh + kn);
            wh1 = *(const uint4*)(pBh + kn + 8);
            wl0 = *(const uint4*)(pBl + kn);
            wl1 = *(const uint4*)(pBl + kn + 8);
        }

        s8v a_h[4], a_l[4], b_h[4], b_l[4];
        #pragma unroll
        for (int mi = 0; mi < 4; ++mi) {
            a_h[mi] = *(const s8v*)&lAh[(wm + mi * 16 + fr) * LDT + fk];
            a_l[mi] = *(const s8v*)&lAl[(wm + mi * 16 + fr) * LDT + fk];
        }
        #pragma unroll
        for (int nj = 0; nj < 4; ++nj) {
            b_h[nj] = *(const s8v*)&lBh[(wn + nj * 16 + fr) * LDT + fk];
            b_l[nj] = *(const s8v*)&lBl[(wn + nj * 16 + fr) * LDT + fk];
        }
        #pragma unroll
        for (int mi = 0; mi < 4; ++mi)
            #pragma unroll
            for (int nj = 0; nj < 4; ++nj) {
                acc[mi][nj] = __builtin_amdgcn_mfma_f32_16x16x32_bf16(
                    a_h[mi], b_h[nj], acc[mi][nj], 0, 0, 0);
                acc[mi][nj] = __builtin_amdgcn_mfma_f32_16x16x32_bf16(
                    a_h[mi], b_l[nj], acc[mi][nj], 0, 0, 0);
                acc[mi][nj] = __builtin_amdgcn_mfma_f32_16x16x32_bf16(
                    a_l[mi], b_h[nj], acc[mi][nj], 0, 0, 0);
            }
    }

    // C/D layout: col = lane&15, row = (lane>>4)*4 + q  [verified gfx950]
    #pragma unroll
    for (int mi = 0; mi < 4; ++mi)
        #pragma unroll
        for (int nj = 0; nj < 4; ++nj) {
            int row0 = bm + wm + mi * 16 + (lane >> 4) * 4;
            int colc = bn + wn + nj * 16 + (lane & 15);
            #pragma unroll
            for (int q = 0; q < 4; ++q) {
                int r = row0 + q;
                if (r < M) C[(size_t)r * Nc + colc] = acc[mi][nj][q];
            }
        }

    // ---- fused alpha epilogue ----
    float av_s[4], av_d[4];
    #pragma unroll
    for (int nj = 0; nj < 4; ++nj) {
        int aidx = bn + wn + nj * 16 + fr;
        av_s[nj] = a_src[aidx];
        av_d[nj] = a_dst[aidx];
    }
    int head = (bn + wn) / CPH;
    #pragma unroll
    for (int mi = 0; mi < 4; ++mi) {
        #pragma unroll
        for (int q = 0; q < 4; ++q) {
            float ps = acc[mi][0][q] * av_s[0] + acc[mi][1][q] * av_s[1]
                     + acc[mi][2][q] * av_s[2] + acc[mi][3][q] * av_s[3];
            float pd = acc[mi][0][q] * av_d[0] + acc[mi][1][q] * av_d[1]
                     + acc[mi][2][q] * av_d[2] + acc[mi][3][q] * av_d[3];
            #pragma unroll
            for (int o = 1; o < 16; o <<= 1) {
                ps += __shfl_xor(ps, o);
                pd += __shfl_xor(pd, o);
            }
            if (fr == 0) {
                int r = bm + wm + mi * 16 + (lane >> 4) * 4 + q;
                if (r < M) {
                    if (CPH == 64) {          // wave == full head: direct store
                        asT[(size_t)head * M + r] = ps;
                        adT[(size_t)head * M + r] = pd;
                    } else {                  // half head: atomic combine
                        atomicAdd(&asT[r], ps);
                        atomicAdd(&adT[r], pd);
                    }
                }
            }
        }
    }
}

// ---------------- channel-sliced softmax-aggregate (R10-measured optimum) ---
// NSLICE=4, fused softmax, fp32 table, GATHER4, VGPR 28 — every probed
// perturbation (NSLICE 1/8, unroll 8, precomputed pex, fp16 table) lost.

template <int NSLICE, int SCH, int F, int HEADS, bool DO_ELU, bool SPLIT>
__global__ __launch_bounds__(256) void gat_aggregate_sliced(
        const float* __restrict__ h,      // [N, F]
        const float* __restrict__ asT,    // [HEADS][N]
        const float* __restrict__ adT,    // [HEADS][N]
        const int* __restrict__ row_ptr,
        const int* __restrict__ col,
        const float* __restrict__ bias,   // [F]
        float* __restrict__ out,          // [N, F]   (SPLIT=false)
        unsigned short* __restrict__ oh,  // [N, F]   (SPLIT=true)
        unsigned short* __restrict__ ol) {
    constexpr int CL = SCH / 4;           // lanes per edge (16 or 8)
    constexpr int E  = 64 / CL;           // parallel edges (4 or 8)
    constexpr int CPH = F / HEADS;        // channels per head
    __shared__ int   s_off[4][64];
    __shared__ float s_p[4][64];
    int slice = blockIdx.x & (NSLICE - 1);
    int ng = blockIdx.x >> 2;             // NSLICE == 4
    int wid = threadIdx.x >> 6, lane = threadIdx.x & 63;
    int v = ng * 4 + wid;
    if (v >= N_NODES) return;
    int head = (slice * SCH) / CPH;       // layers 1/2: slice == head; layer 3: 0
    int eg = lane / CL, cl = lane % CL;
    int r0 = row_ptr[v], r1 = row_ptr[v + 1];
    float ad = adT[head * N_NODES + v];
    const float* asrc = asT + head * N_NODES;
    float acc[4] = {};
    float lsum = 0.f;
    const char* hb = (const char*)(h + slice * SCH + cl * 4);

#define GATHER4(gg)                                                        \
    {                                                                      \
        int k0 = ((gg) + 0) * E + eg;                                      \
        int k1 = ((gg) + 1) * E + eg;                                      \
        int k2 = ((gg) + 2) * E + eg;                                      \
        int k3 = ((gg) + 3) * E + eg;                                      \
        float p0 = s_p[wid][k0]; int o0 = s_off[wid][k0];                  \
        float p1 = s_p[wid][k1]; int o1 = s_off[wid][k1];                  \
        float p2 = s_p[wid][k2]; int o2 = s_off[wid][k2];                  \
        float p3 = s_p[wid][k3]; int o3 = s_off[wid][k3];                  \
        float4 h0 = *(const float4*)(hb + o0);                             \
        float4 h1 = *(const float4*)(hb + o1);                             \
        float4 h2 = *(const float4*)(hb + o2);                             \
        float4 h3 = *(const float4*)(hb + o3);                             \
        acc[0] = fmaf(p0, h0.x, acc[0]);                                   \
        acc[1] = fmaf(p0, h0.y, acc[1]);                                   \
        acc[2] = fmaf(p0, h0.z, acc[2]);                                   \
        acc[3] = fmaf(p0, h0.w, acc[3]);                                   \
        acc[0] = fmaf(p1, h1.x, acc[0]);                                   \
        acc[1] = fmaf(p1, h1.y, acc[1]);                                   \
        acc[2] = fmaf(p1, h1.z, acc[2]);                                   \
        acc[3] = fmaf(p1, h1.w, acc[3]);                                   \
        acc[0] = fmaf(p2, h2.x, acc[0]);                                   \
        acc[1] = fmaf(p2, h2.y, acc[1]);                                   \
        acc[2] = fmaf(p2, h2.z, acc[2]);                                   \
        acc[3] = fmaf(p2, h2.w, acc[3]);                                   \
        acc[0] = fmaf(p3, h3.x, acc[0]);                                   \
        acc[1] = fmaf(p3, h3.y, acc[1]);                                   \
        acc[2] = fmaf(p3, h3.z, acc[2]);                                   \
        acc[3] = fmaf(p3, h3.w, acc[3]);                                   \
    }

    for (int base = r0; base < r1; base += 64) {
        int j = base + lane;
        bool valid = j < r1;
        int s = col[valid ? j : r0];
        float e = asrc[s] + ad;
        e = (e > 0.f) ? e : NEG_SLOPE * e;
        float p = valid ? __expf(e) : 0.f;
        lsum += p;
        s_p[wid][lane] = p;
        s_off[wid][lane] = s * (F * 4);   // byte offset of row s

        int nk = min(64, r1 - base);
        int nkg = (nk + E - 1) / E;       // <= 64/E
        int g = 0;
        for (; g + 4 <= nkg; g += 4) GATHER4(g);
        if (g < nkg) GATHER4(g);          // ragged tail: extra groups have p==0
    }
#undef GATHER4

    // full-wave softmax denominator
    #pragma unroll
    for (int o = 32; o; o >>= 1) lsum += __shfl_xor(lsum, o);
    // reduce acc across edge groups (lanes differing in bits >= log2(CL))
    #pragma unroll
    for (int c = 0; c < 4; ++c) {
        #pragma unroll
        for (int o = CL; o < 64; o <<= 1) acc[c] += __shfl_xor(acc[c], o);
    }
    if (eg == 0) {
        float inv = 1.f / (lsum + 1e-16f);
        int ch0 = slice * SCH + cl * 4;
        float o4[4];
        #pragma unroll
        for (int c = 0; c < 4; ++c) {
            float o = acc[c] * inv + bias[ch0 + c];
            if (DO_ELU) o = (o > 0.f) ? o : expm1f(o);
            o4[c] = o;
        }
        if constexpr (SPLIT) {
            ushort4 hv4, lv4;
            hv4.x = bf_hi(o4[0]); lv4.x = bf_hi(o4[0] - bf_f(hv4.x));
            hv4.y = bf_hi(o4[1]); lv4.y = bf_hi(o4[1] - bf_f(hv4.y));
            hv4.z = bf_hi(o4[2]); lv4.z = bf_hi(o4[2] - bf_f(hv4.z));
            hv4.w = bf_hi(o4[3]); lv4.w = bf_hi(o4[3] - bf_f(hv4.w));
            *(ushort4*)&oh[(size_t)v * F + ch0] = hv4;
            *(ushort4*)&ol[(size_t)v * F + ch0] = lv4;
        } else {
            *(float4*)&out[(size_t)v * F + ch0] =
                make_float4(o4[0], o4[1], o4[2], o4[3]);
        }
    }
}

// ---------------- global mean pool: 4-way row-split + atomic combine --------

__global__ void pool_mean4(const float* __restrict__ hout, const int* __restrict__ gstart,
                           float* __restrict__ gout) {
    int g = blockIdx.x;       // 64
    int q = blockIdx.y;       // 4 row-quarters
    int c = threadIdx.x;      // 128 channels
    int off = gstart[g], end = gstart[g + 1];
    float inv = 1.f / fmaxf((float)(end - off), 1.0f);
    float s = 0.f;
    for (int i = off + q; i < end; i += 4) s += hout[(size_t)i * 128 + c];
    atomicAdd(&gout[g * 128 + c], s * inv);
}

// ---------------- launch ----------------

static inline size_t align_up(size_t x, size_t a) { return (x + a - 1) & ~(a - 1); }

extern "C" void kernel_launch(void* const* d_in, const int* in_sizes, int n_in,
                              void* d_out, int out_size, void* d_ws, size_t ws_size,
                              hipStream_t stream) {
    const float* x   = (const float*)d_in[0];
    const int*   ei  = (const int*)d_in[1];
    const int*   bat = (const int*)d_in[2];
    const float* W1  = (const float*)d_in[3];
    const float* as1 = (const float*)d_in[4];
    const float* ad1 = (const float*)d_in[5];
    const float* b1  = (const float*)d_in[6];
    const float* W2  = (const float*)d_in[7];
    const float* as2 = (const float*)d_in[8];
    const float* ad2 = (const float*)d_in[9];
    const float* b2  = (const float*)d_in[10];
    const float* W3  = (const float*)d_in[11];
    const float* as3 = (const float*)d_in[12];
    const float* ad3 = (const float*)d_in[13];
    const float* b3  = (const float*)d_in[14];

    float* gout = (float*)d_out;                     // [G,128]
    float* hout = (float*)d_out + G_GRAPHS * 128;    // [N,128]

    char* w = (char*)d_ws;
    size_t o = 0;
    float* bufA = (float*)(w + o);           o = align_up(o + (size_t)N_NODES * 256 * 4, 256);
    unsigned short* Bh = (unsigned short*)(w + o); o = align_up(o + (size_t)N_NODES * 256 * 2, 256);
    unsigned short* Bl = (unsigned short*)(w + o); o = align_up(o + (size_t)N_NODES * 256 * 2, 256);
    unsigned short* xh = (unsigned short*)(w + o); o = align_up(o + (size_t)N_NODES * 128 * 2, 256);
    unsigned short* xl = (unsigned short*)(w + o); o = align_up(o + (size_t)N_NODES * 128 * 2, 256);
    unsigned short* Wt1h = (unsigned short*)(w + o); o = align_up(o + (size_t)256 * 128 * 2, 256);
    unsigned short* Wt1l = (unsigned short*)(w + o); o = align_up(o + (size_t)256 * 128 * 2, 256);
    unsigned short* Wt2h = (unsigned short*)(w + o); o = align_up(o + (size_t)256 * 256 * 2, 256);
    unsigned short* Wt2l = (unsigned short*)(w + o); o = align_up(o + (size_t)256 * 256 * 2, 256);
    unsigned short* Wt3h = (unsigned short*)(w + o); o = align_up(o + (size_t)128 * 256 * 2, 256);
    unsigned short* Wt3l = (unsigned short*)(w + o); o = align_up(o + (size_t)128 * 256 * 2, 256);
    // per-layer alpha buffers (only asv3/adv3 need pre-zeroing)
    float* alpha = (float*)(w + o);
    float* asv1 = alpha;                  // [4][N]
    float* adv1 = alpha + 4 * N_NODES;    // [4][N]
    float* asv2 = alpha + 8 * N_NODES;    // [4][N]
    float* adv2 = alpha + 12 * N_NODES;   // [4][N]
    float* asv3 = alpha + 16 * N_NODES;   // [N]
    float* adv3 = alpha + 17 * N_NODES;   // [N]
    o = align_up(o + (size_t)18 * N_NODES * 4, 256);
    int* row_ptr = (int*)(w + o);  o = align_up(o + (size_t)(N_NODES + 1) * 4, 256);
    int* col     = (int*)(w + o);  o = align_up(o + (size_t)ET_EDGES * 4, 256);
    int* cnt     = (int*)(w + o);  o += (size_t)N_NODES * 4;        // cnt+cur contiguous
    int* cur     = (int*)(w + o);  o = align_up(o + (size_t)N_NODES * 4, 256);
    int* gstart  = (int*)(w + o);  o = align_up(o + (size_t)(G_GRAPHS + 1) * 4, 256);

    // ---- fused prep (splits + zeroing) + CSR build ----
    {
        int total = 640000 + 32768 + 65536 + 32768 + 10000 + 2048 + 10000;
        prep_split<<<(total + 255) / 256, 256, 0, stream>>>(
            x, W1, W2, W3, xh, xl, Wt1h, Wt1l, Wt2h, Wt2l, Wt3h, Wt3l, cnt, gout, asv3);
    }
    hist_dst<<<(ET_EDGES + 255) / 256, 256, 0, stream>>>(ei, cnt, bat, gstart);
    scan_rowptr<<<1, 1024, 0, stream>>>(cnt, row_ptr);
    fill_csr<<<(ET_EDGES + 255) / 256, 256, 0, stream>>>(ei, row_ptr, cur, col);

    int gm = (N_NODES + 127) / 128;   // 157
    int nb = (N_NODES + 3) / 4;       // 4 nodes per block
    int nbs = nb * 4;                 // x4 channel slices

    // ---- layer 1: 128 -> 4x64 (alpha fused into GEMM epilogue) ----
    gemm_split<64><<<dim3(gm, 2), 256, 0, stream>>>(
        xh, xl, Wt1h, Wt1l, bufA, N_NODES, 256, 128, as1, ad1, asv1, adv1);
    gat_aggregate_sliced<4, 64, 256, 4, true, true><<<nbs, 256, 0, stream>>>(
        bufA, asv1, adv1, row_ptr, col, b1, nullptr, Bh, Bl);

    // ---- layer 2: 256 -> 4x64 ----
    gemm_split<64><<<dim3(gm, 2), 256, 0, stream>>>(
        Bh, Bl, Wt2h, Wt2l, bufA, N_NODES, 256, 256, as2, ad2, asv2, adv2);
    gat_aggregate_sliced<4, 64, 256, 4, true, true><<<nbs, 256, 0, stream>>>(
        bufA, asv2, adv2, row_ptr, col, b2, nullptr, Bh, Bl);

    // ---- layer 3: 256 -> 128 (1 head; half-head waves -> atomics) ----
    gemm_split<128><<<dim3(gm, 1), 256, 0, stream>>>(
        Bh, Bl, Wt3h, Wt3l, bufA, N_NODES, 128, 256, as3, ad3, asv3, adv3);
    gat_aggregate_sliced<4, 32, 128, 1, false, false><<<nbs, 256, 0, stream>>>(
        bufA, asv3, adv3, row_ptr, col, b3, hout, nullptr, nullptr);

    // ---- global mean pool ----
    pool_mean4<<<dim3(G_GRAPHS, 4), 128, 0, stream>>>(hout, gstart, gout);
}